// Round 1
// baseline (741.181 us; speedup 1.0000x reference)
//
#include <hip/hip_runtime.h>
#include <math.h>

#define HH 128
#define WW 128
#define HW 16384
#define NLINES 49152
#define KJ 300
#define SENT 90000
#define THRESHV 0.008f
#define CAND_CAP 8192
#define BITWORDS 2816
#define BM 64
#define BN 64
#define BK 16

__device__ __forceinline__ float sigm(float x){ return 1.0f/(1.0f+expf(-x)); }

// ---------------- 1. activations + HAFM line decode ----------------
__global__ void k_prep(const float* __restrict__ hm, float* __restrict__ jloc,
                       float* __restrict__ lines, int* __restrict__ cand_count){
  int i = blockIdx.x*blockDim.x + threadIdx.x;
  if (i == 0) *cand_count = 0;
  if (i >= HW) return;
  float h0 = hm[i], h1 = hm[HW+i], h2 = hm[2*HW+i], h3 = hm[3*HW+i], h4 = hm[4*HW+i];
  float h5 = hm[5*HW+i], h6 = hm[6*HW+i];
  float a0 = sigm(h0), a1 = sigm(h1), a2 = sigm(h2);
  float dist = sigm(h3), bias = sigm(h4);
  float mx = fmaxf(h5,h6);
  float e5 = expf(h5-mx), e6 = expf(h6-mx);
  jloc[i] = e6/(e5+e6);
  const float PI = 3.14159265358979323846f;
  float ang0 = (a0-0.5f)*(2.0f*PI);
  float c0 = cosf(ang0), s0 = sinf(ang0);
  float t1 = tanf(a1*(0.5f*PI));
  float t2 = tanf(-a2*(0.5f*PI));
  int y = i >> 7, x = i & 127;
  float fx = (float)x, fy = (float)y;
  #pragma unroll
  for (int c=0;c<3;c++){
    float d = fminf(fmaxf(dist + bias*(float)(c-1), 0.0f), 1.0f);
    float ds = d*5.0f;
    float x1 = fminf(fmaxf((c0 - s0*t1)*ds + fx, 0.0f), 127.0f);
    float y1 = fminf(fmaxf((s0 + c0*t1)*ds + fy, 0.0f), 127.0f);
    float x2 = fminf(fmaxf((c0 - s0*t2)*ds + fx, 0.0f), 127.0f);
    float y2 = fminf(fmaxf((s0 + c0*t2)*ds + fy, 0.0f), 127.0f);
    ((float4*)lines)[c*HW + i] = make_float4(x1,y1,x2,y2);
  }
}

// ---------------- 2. 3x3 NMS + compact candidates > THRESH ----------------
__global__ void k_nms(const float* __restrict__ jloc, unsigned long long* __restrict__ cand,
                      int* __restrict__ cand_count){
  int i = blockIdx.x*blockDim.x + threadIdx.x;
  if (i >= HW) return;
  int y = i >> 7, x = i & 127;
  float v = jloc[i];
  float m = v;
  for (int dy=-1; dy<=1; dy++){
    int ny = y + dy; if (ny < 0 || ny >= HH) continue;
    for (int dx=-1; dx<=1; dx++){
      int nx = x + dx; if (nx < 0 || nx >= WW) continue;
      m = fmaxf(m, jloc[ny*WW + nx]);
    }
  }
  if (v == m && v > THRESHV){
    int pos = atomicAdd(cand_count, 1);
    if (pos < CAND_CAP){
      unsigned int vb = __float_as_uint(v);
      cand[pos] = ((unsigned long long)vb << 32) | (unsigned long long)(0xFFFFFFFFu - (unsigned)i);
    }
  }
}

// ---------------- 3. single-block bitonic top-K -> junction coords ----------------
__global__ __launch_bounds__(1024) void k_topk(const unsigned long long* __restrict__ cand,
    const int* __restrict__ cand_count, const float* __restrict__ hm, float* __restrict__ junc){
  __shared__ unsigned long long s[CAND_CAP];
  int t = threadIdx.x;
  int count = *cand_count; if (count > CAND_CAP) count = CAND_CAP;
  for (int i=t; i<CAND_CAP; i+=1024) s[i] = (i < count) ? cand[i] : 0ull;
  __syncthreads();
  for (int k=2; k<=CAND_CAP; k<<=1){
    for (int j=k>>1; j>0; j>>=1){
      for (int i=t; i<CAND_CAP; i+=1024){
        int ixj = i ^ j;
        if (ixj > i){
          unsigned long long a = s[i], b = s[ixj];
          bool desc = ((i & k) == 0);
          if (desc ? (a < b) : (a > b)){ s[i] = b; s[ixj] = a; }
        }
      }
      __syncthreads();
    }
  }
  if (t < KJ){
    float jx = 1e6f, jy = 1e6f;
    if (t < count){
      unsigned idx = 0xFFFFFFFFu - (unsigned)(s[t] & 0xFFFFFFFFull);
      int yy = (int)(idx >> 7), xx = (int)(idx & 127u);
      jx = (float)xx + sigm(hm[7*HW + idx]);
      jy = (float)yy + sigm(hm[8*HW + idx]);
    }
    junc[2*t] = jx; junc[2*t+1] = jy;
  }
}

// ---------------- 4. junction-endpoint argmin matching ----------------
__global__ void k_match(const float* __restrict__ lines, const float* __restrict__ junc,
                        int* __restrict__ ids){
  __shared__ float jx[KJ], jy[KJ];
  int t = threadIdx.x;
  for (int k=t; k<KJ; k+=blockDim.x){ jx[k] = junc[2*k]; jy[k] = junc[2*k+1]; }
  __syncthreads();
  int n = blockIdx.x*blockDim.x + t;
  if (n >= NLINES) return;
  float4 L = ((const float4*)lines)[n];
  float b1 = 1e30f, b2 = 1e30f; int j1 = 0, j2 = 0;
  for (int k=0; k<KJ; k++){
    float dx1 = jx[k]-L.x, dy1 = jy[k]-L.y;
    float d1 = dx1*dx1 + dy1*dy1;
    float dx2 = jx[k]-L.z, dy2 = jy[k]-L.w;
    float d2 = dx2*dx2 + dy2*dy2;
    if (d1 < b1){ b1 = d1; j1 = k; }
    if (d2 < b2){ b2 = d2; j2 = k; }
  }
  int lo = min(j1,j2), hi = max(j1,j2);
  ids[n] = (lo < hi) ? (lo*KJ + hi) : SENT;
}

// ---------------- 5. sorted unique via bitmap + block scan ----------------
__global__ __launch_bounds__(1024) void k_unique(const int* __restrict__ ids,
    int* __restrict__ uid_list, int* __restrict__ mcount){
  __shared__ unsigned bm[BITWORDS];
  __shared__ int sums[1024];
  int t = threadIdx.x;
  for (int i=t; i<BITWORDS; i+=1024) bm[i] = 0u;
  __syncthreads();
  for (int n=t; n<NLINES; n+=1024){
    int id = ids[n];
    if (id < SENT) atomicOr(&bm[id>>5], 1u << (id & 31));
  }
  __syncthreads();
  int w0 = t*3;
  int local = 0;
  for (int w=w0; w<w0+3; w++) if (w < BITWORDS) local += __popc(bm[w]);
  sums[t] = local;
  __syncthreads();
  for (int off=1; off<1024; off<<=1){
    int v = sums[t];
    int add = (t >= off) ? sums[t-off] : 0;
    __syncthreads();
    sums[t] = v + add;
    __syncthreads();
  }
  int base = sums[t] - local;
  for (int w=w0; w<w0+3; w++){
    if (w >= BITWORDS) break;
    unsigned bits = bm[w];
    while (bits){
      int b = __ffs(bits) - 1;
      uid_list[base++] = w*32 + b;
      bits &= bits - 1;
    }
  }
  if (t == 1023) *mcount = sums[1023];
}

// ---------------- 6. line_coords output (+ zero scores past M) ----------------
__global__ void k_coords(const int* __restrict__ uid_list, const int* __restrict__ mcount,
                         const float* __restrict__ junc, float* __restrict__ out){
  int r = blockIdx.x*blockDim.x + threadIdx.x;
  if (r >= NLINES) return;
  int M = *mcount;
  float4 v = make_float4(0.f,0.f,0.f,0.f);
  if (r < M){
    int id = uid_list[r];
    int lo = id / KJ, hi = id % KJ;
    v = make_float4(junc[2*lo], junc[2*lo+1], junc[2*hi], junc[2*hi+1]);
  } else {
    out[4*NLINES + r] = 0.0f;
  }
  ((float4*)out)[r] = v;
}

// ---------------- 7. LOI feature map: [128,256]@[256,HW] -> pixel-major [HW][128] ----------------
#define LOI_TP 32
__global__ __launch_bounds__(256) void k_loi(const float* __restrict__ feat,
    const float* __restrict__ fc1w, const float* __restrict__ fc1b, float* __restrict__ loi){
  __shared__ float sf[256*LOI_TP];
  int p0 = blockIdx.x * LOI_TP;
  int t = threadIdx.x;
  for (int i=t; i<256*LOI_TP; i+=256){
    int c = i / LOI_TP, p = i % LOI_TP;
    sf[i] = feat[c*HW + p0 + p];
  }
  __syncthreads();
  int p = t & 31;
  int og = t >> 5;       // 8 groups of 16 output channels
  float acc[16];
  #pragma unroll
  for (int u=0; u<16; u++) acc[u] = 0.0f;
  for (int c=0; c<256; c++){
    float f = sf[c*LOI_TP + p];
    #pragma unroll
    for (int u=0; u<16; u++) acc[u] += fc1w[(og*16+u)*256 + c] * f;
  }
  float* dst = &loi[(size_t)(p0+p)*128 + og*16];
  #pragma unroll
  for (int u=0; u<16; u++) dst[u] = acc[u] + fc1b[og*16+u];
}

// ---------------- 8. per-line bilinear sampling + maxpool4 -> 1024 feats ----------------
__global__ __launch_bounds__(128) void k_sample(const float* __restrict__ out,
    const float* __restrict__ loi, const int* __restrict__ mcount,
    float* __restrict__ fbuf, float* __restrict__ logit, int chunk0){
  int b = blockIdx.x;
  int t = threadIdx.x;            // channel 0..127
  if (t == 0) logit[b] = 0.0f;    // always zero (before early exit)
  int r = chunk0 + b;
  int M = *mcount;
  if (r >= M) return;
  float4 C = ((const float4*)out)[r];  // x1,y1,x2,y2
  float gmax[8];
  #pragma unroll
  for (int g=0; g<8; g++) gmax[g] = -1e30f;
  for (int s=0; s<32; s++){
    float tt = (float)s * (1.0f/31.0f);
    float px = C.x*tt + C.z*(1.0f-tt);
    float py = C.y*tt + C.w*(1.0f-tt);
    px = fminf(fmaxf(px, 0.0f), 127.0f);
    py = fminf(fmaxf(py, 0.0f), 127.0f);
    float x0 = floorf(px), y0 = floorf(py);
    int x0i = (int)x0, y0i = (int)y0;
    int x1i = min(x0i+1, 127), y1i = min(y0i+1, 127);
    float wx = px - x0, wy = py - y0;
    const float* p00 = loi + ((size_t)(y0i*WW + x0i))*128;
    const float* p01 = loi + ((size_t)(y0i*WW + x1i))*128;
    const float* p10 = loi + ((size_t)(y1i*WW + x0i))*128;
    const float* p11 = loi + ((size_t)(y1i*WW + x1i))*128;
    float v = p00[t]*(1.0f-wx)*(1.0f-wy) + p01[t]*wx*(1.0f-wy)
            + p10[t]*(1.0f-wx)*wy + p11[t]*wx*wy;
    gmax[s>>2] = fmaxf(gmax[s>>2], v);
  }
  float* dst = &fbuf[(size_t)b*1024 + t*8];
  #pragma unroll
  for (int g=0; g<8; g++) dst[g] = gmax[g];
}

// ---------------- 9. GEMM1: h1 = relu(f @ w1.T + b1) ----------------
__global__ __launch_bounds__(256) void k_gemm_relu(const float* __restrict__ A,
    const float* __restrict__ Wt, const float* __restrict__ bias,
    float* __restrict__ Cout, const int* __restrict__ mcount, int chunk0){
  int M = *mcount;
  int row0 = blockIdx.x * BM;
  int col0 = blockIdx.y * BN;
  if (chunk0 + row0 >= M) return;
  __shared__ float As[BK][BM+4];
  __shared__ float Bs[BK][BN+4];
  int t = threadIdx.x;
  int tx = t & 15, ty = t >> 4;
  float acc[4][4];
  #pragma unroll
  for (int u=0; u<4; u++)
    #pragma unroll
    for (int v=0; v<4; v++) acc[u][v] = 0.0f;
  int rr = t >> 2;
  int kp = (t & 3) * 4;
  for (int k0=0; k0<1024; k0+=BK){
    float4 av = *(const float4*)&A[(size_t)(row0+rr)*1024 + k0 + kp];
    As[kp+0][rr]=av.x; As[kp+1][rr]=av.y; As[kp+2][rr]=av.z; As[kp+3][rr]=av.w;
    float4 bv = *(const float4*)&Wt[(size_t)(col0+rr)*1024 + k0 + kp];
    Bs[kp+0][rr]=bv.x; Bs[kp+1][rr]=bv.y; Bs[kp+2][rr]=bv.z; Bs[kp+3][rr]=bv.w;
    __syncthreads();
    #pragma unroll
    for (int kk=0; kk<BK; kk++){
      float4 a = *(const float4*)&As[kk][ty*4];
      float4 b = *(const float4*)&Bs[kk][tx*4];
      acc[0][0]+=a.x*b.x; acc[0][1]+=a.x*b.y; acc[0][2]+=a.x*b.z; acc[0][3]+=a.x*b.w;
      acc[1][0]+=a.y*b.x; acc[1][1]+=a.y*b.y; acc[1][2]+=a.y*b.z; acc[1][3]+=a.y*b.w;
      acc[2][0]+=a.z*b.x; acc[2][1]+=a.z*b.y; acc[2][2]+=a.z*b.z; acc[2][3]+=a.z*b.w;
      acc[3][0]+=a.w*b.x; acc[3][1]+=a.w*b.y; acc[3][2]+=a.w*b.z; acc[3][3]+=a.w*b.w;
    }
    __syncthreads();
  }
  #pragma unroll
  for (int u=0; u<4; u++){
    int row = row0 + ty*4 + u;
    int col = col0 + tx*4;
    float4 o;
    o.x = fmaxf(acc[u][0] + bias[col+0], 0.0f);
    o.y = fmaxf(acc[u][1] + bias[col+1], 0.0f);
    o.z = fmaxf(acc[u][2] + bias[col+2], 0.0f);
    o.w = fmaxf(acc[u][3] + bias[col+3], 0.0f);
    *(float4*)&Cout[(size_t)row*1024 + col] = o;
  }
}

// ---------------- 10. GEMM2 + w3 dot fused: partial logits via atomicAdd ----------------
__global__ __launch_bounds__(256) void k_gemm_final(const float* __restrict__ A,
    const float* __restrict__ Wt, const float* __restrict__ bias,
    const float* __restrict__ w3, float* __restrict__ logit,
    const int* __restrict__ mcount, int chunk0){
  int M = *mcount;
  int row0 = blockIdx.x * BM;
  int col0 = blockIdx.y * BN;
  if (chunk0 + row0 >= M) return;
  __shared__ float As[BK][BM+4];
  __shared__ float Bs[BK][BN+4];
  __shared__ float red[BM][17];
  int t = threadIdx.x;
  int tx = t & 15, ty = t >> 4;
  float acc[4][4];
  #pragma unroll
  for (int u=0; u<4; u++)
    #pragma unroll
    for (int v=0; v<4; v++) acc[u][v] = 0.0f;
  int rr = t >> 2;
  int kp = (t & 3) * 4;
  for (int k0=0; k0<1024; k0+=BK){
    float4 av = *(const float4*)&A[(size_t)(row0+rr)*1024 + k0 + kp];
    As[kp+0][rr]=av.x; As[kp+1][rr]=av.y; As[kp+2][rr]=av.z; As[kp+3][rr]=av.w;
    float4 bv = *(const float4*)&Wt[(size_t)(col0+rr)*1024 + k0 + kp];
    Bs[kp+0][rr]=bv.x; Bs[kp+1][rr]=bv.y; Bs[kp+2][rr]=bv.z; Bs[kp+3][rr]=bv.w;
    __syncthreads();
    #pragma unroll
    for (int kk=0; kk<BK; kk++){
      float4 a = *(const float4*)&As[kk][ty*4];
      float4 b = *(const float4*)&Bs[kk][tx*4];
      acc[0][0]+=a.x*b.x; acc[0][1]+=a.x*b.y; acc[0][2]+=a.x*b.z; acc[0][3]+=a.x*b.w;
      acc[1][0]+=a.y*b.x; acc[1][1]+=a.y*b.y; acc[1][2]+=a.y*b.z; acc[1][3]+=a.y*b.w;
      acc[2][0]+=a.z*b.x; acc[2][1]+=a.z*b.y; acc[2][2]+=a.z*b.z; acc[2][3]+=a.z*b.w;
      acc[3][0]+=a.w*b.x; acc[3][1]+=a.w*b.y; acc[3][2]+=a.w*b.z; acc[3][3]+=a.w*b.w;
    }
    __syncthreads();
  }
  #pragma unroll
  for (int u=0; u<4; u++){
    int col = col0 + tx*4;
    float part = 0.0f;
    #pragma unroll
    for (int v=0; v<4; v++){
      float h = fmaxf(acc[u][v] + bias[col+v], 0.0f);
      part += h * w3[col+v];
    }
    red[ty*4+u][tx] = part;
  }
  __syncthreads();
  if (t < BM){
    float s = 0.0f;
    #pragma unroll
    for (int j=0; j<16; j++) s += red[t][j];
    atomicAdd(&logit[row0 + t], s);
  }
}

// ---------------- 11. final sigmoid scores ----------------
__global__ void k_score(const float* __restrict__ logit, const float* __restrict__ b3,
                        const int* __restrict__ mcount, float* __restrict__ out, int chunk0){
  int i = blockIdx.x*blockDim.x + threadIdx.x;
  int r = chunk0 + i;
  if (r >= NLINES) return;
  int M = *mcount;
  if (r >= M) return;
  float lg = logit[i] + b3[0];
  out[4*NLINES + r] = 1.0f/(1.0f + expf(-lg));
}

extern "C" void kernel_launch(void* const* d_in, const int* in_sizes, int n_in,
                              void* d_out, int out_size, void* d_ws, size_t ws_size,
                              hipStream_t stream){
  const float* features = (const float*)d_in[0];
  const float* heatmaps = (const float*)d_in[1];
  const float* fc1_w    = (const float*)d_in[2];
  const float* fc1_b    = (const float*)d_in[3];
  const float* w1       = (const float*)d_in[4];
  const float* b1       = (const float*)d_in[5];
  const float* w2       = (const float*)d_in[6];
  const float* b2       = (const float*)d_in[7];
  const float* w3       = (const float*)d_in[8];
  const float* b3       = (const float*)d_in[9];
  float* out = (float*)d_out;

  char* ws = (char*)d_ws;
  size_t off = 0;
  auto alloc = [&](size_t bytes) -> void* {
    void* p = ws + off;
    off = (off + bytes + 255) & ~(size_t)255;
    return p;
  };
  float* jloc      = (float*)alloc(HW*4);
  float* lines     = (float*)alloc((size_t)NLINES*16);
  unsigned long long* cand = (unsigned long long*)alloc(CAND_CAP*8);
  int*   cand_count= (int*)alloc(4);
  float* junc      = (float*)alloc(KJ*2*4);
  int*   ids       = (int*)alloc((size_t)NLINES*4);
  int*   uid_list  = (int*)alloc((size_t)NLINES*4);
  int*   mcount    = (int*)alloc(4);
  float* loi       = (float*)alloc((size_t)HW*128*4);
  size_t fixed = off;

  // pick largest chunk that fits the workspace (constant across calls)
  const int chunk_opts[7] = {49152, 24576, 12288, 8192, 4096, 2048, 1024};
  int CHUNK = 1024;
  for (int ci=0; ci<7; ci++){
    size_t need = fixed + (size_t)chunk_opts[ci]*1024*4*2 + (size_t)chunk_opts[ci]*4 + 1024;
    if (need <= ws_size){ CHUNK = chunk_opts[ci]; break; }
  }
  float* fbuf  = (float*)alloc((size_t)CHUNK*1024*4);
  float* h1buf = (float*)alloc((size_t)CHUNK*1024*4);
  float* logit = (float*)alloc((size_t)CHUNK*4);

  k_prep <<<HW/256, 256, 0, stream>>>(heatmaps, jloc, lines, cand_count);
  k_nms  <<<HW/256, 256, 0, stream>>>(jloc, cand, cand_count);
  k_topk <<<1, 1024, 0, stream>>>(cand, cand_count, heatmaps, junc);
  k_match<<<NLINES/256, 256, 0, stream>>>(lines, junc, ids);
  k_unique<<<1, 1024, 0, stream>>>(ids, uid_list, mcount);
  k_coords<<<NLINES/256, 256, 0, stream>>>(uid_list, mcount, junc, out);
  k_loi  <<<HW/LOI_TP, 256, 0, stream>>>(features, fc1_w, fc1_b, loi);

  int nchunk = NLINES / CHUNK;
  for (int ci=0; ci<nchunk; ci++){
    int chunk0 = ci * CHUNK;
    k_sample<<<CHUNK, 128, 0, stream>>>(out, loi, mcount, fbuf, logit, chunk0);
    dim3 g1(CHUNK/BM, 1024/BN);
    k_gemm_relu <<<g1, 256, 0, stream>>>(fbuf, w1, b1, h1buf, mcount, chunk0);
    k_gemm_final<<<g1, 256, 0, stream>>>(h1buf, w2, b2, w3, logit, mcount, chunk0);
    k_score<<<CHUNK/256, 256, 0, stream>>>(logit, b3, mcount, out, chunk0);
  }
}

// Round 2
// 566.722 us; speedup vs baseline: 1.3078x; 1.3078x over previous
//
#include <hip/hip_runtime.h>
#include <math.h>

#define HH 128
#define WW 128
#define HW 16384
#define NLINES 49152
#define KJ 300
#define SENT 90000
#define THRESHV 0.008f
#define CAND_CAP 8192
#define BITWORDS 2816

typedef __attribute__((ext_vector_type(8))) short bf16x8;
typedef __attribute__((ext_vector_type(4))) float f32x4;

__device__ __forceinline__ float sigm(float x){ return 1.0f/(1.0f+expf(-x)); }

__device__ __forceinline__ short tobf(float f){
  unsigned u = __float_as_uint(f);
  unsigned r = u + 0x7FFFu + ((u >> 16) & 1u);
  return (short)(r >> 16);
}

// ---------------- 1. activations + HAFM line decode ----------------
__global__ void k_prep(const float* __restrict__ hm, float* __restrict__ jloc,
                       float* __restrict__ lines, int* __restrict__ cand_count){
  int i = blockIdx.x*blockDim.x + threadIdx.x;
  if (i == 0) *cand_count = 0;
  if (i >= HW) return;
  float h0 = hm[i], h1 = hm[HW+i], h2 = hm[2*HW+i], h3 = hm[3*HW+i], h4 = hm[4*HW+i];
  float h5 = hm[5*HW+i], h6 = hm[6*HW+i];
  float a0 = sigm(h0), a1 = sigm(h1), a2 = sigm(h2);
  float dist = sigm(h3), bias = sigm(h4);
  float mx = fmaxf(h5,h6);
  float e5 = expf(h5-mx), e6 = expf(h6-mx);
  jloc[i] = e6/(e5+e6);
  const float PI = 3.14159265358979323846f;
  float ang0 = (a0-0.5f)*(2.0f*PI);
  float c0 = cosf(ang0), s0 = sinf(ang0);
  float t1 = tanf(a1*(0.5f*PI));
  float t2 = tanf(-a2*(0.5f*PI));
  int y = i >> 7, x = i & 127;
  float fx = (float)x, fy = (float)y;
  #pragma unroll
  for (int c=0;c<3;c++){
    float d = fminf(fmaxf(dist + bias*(float)(c-1), 0.0f), 1.0f);
    float ds = d*5.0f;
    float x1 = fminf(fmaxf((c0 - s0*t1)*ds + fx, 0.0f), 127.0f);
    float y1 = fminf(fmaxf((s0 + c0*t1)*ds + fy, 0.0f), 127.0f);
    float x2 = fminf(fmaxf((c0 - s0*t2)*ds + fx, 0.0f), 127.0f);
    float y2 = fminf(fmaxf((s0 + c0*t2)*ds + fy, 0.0f), 127.0f);
    ((float4*)lines)[c*HW + i] = make_float4(x1,y1,x2,y2);
  }
}

// ---------------- 2. 3x3 NMS + compact candidates > THRESH ----------------
__global__ void k_nms(const float* __restrict__ jloc, unsigned long long* __restrict__ cand,
                      int* __restrict__ cand_count){
  int i = blockIdx.x*blockDim.x + threadIdx.x;
  if (i >= HW) return;
  int y = i >> 7, x = i & 127;
  float v = jloc[i];
  float m = v;
  for (int dy=-1; dy<=1; dy++){
    int ny = y + dy; if (ny < 0 || ny >= HH) continue;
    for (int dx=-1; dx<=1; dx++){
      int nx = x + dx; if (nx < 0 || nx >= WW) continue;
      m = fmaxf(m, jloc[ny*WW + nx]);
    }
  }
  if (v == m && v > THRESHV){
    int pos = atomicAdd(cand_count, 1);
    if (pos < CAND_CAP){
      unsigned int vb = __float_as_uint(v);
      cand[pos] = ((unsigned long long)vb << 32) | (unsigned long long)(0xFFFFFFFFu - (unsigned)i);
    }
  }
}

// ---------------- 3. single-block bitonic top-K (adaptive length) ----------------
__global__ __launch_bounds__(1024) void k_topk(const unsigned long long* __restrict__ cand,
    const int* __restrict__ cand_count, const float* __restrict__ hm, float* __restrict__ junc){
  __shared__ unsigned long long s[CAND_CAP];
  int t = threadIdx.x;
  int count = *cand_count; if (count > CAND_CAP) count = CAND_CAP;
  int n2 = 512;
  while (n2 < count) n2 <<= 1;   // next pow2 >= count, >= 512 (>= KJ)
  for (int i=t; i<n2; i+=1024) s[i] = (i < count) ? cand[i] : 0ull;
  __syncthreads();
  for (int k=2; k<=n2; k<<=1){
    for (int j=k>>1; j>0; j>>=1){
      for (int i=t; i<n2; i+=1024){
        int ixj = i ^ j;
        if (ixj > i){
          unsigned long long a = s[i], b = s[ixj];
          bool desc = ((i & k) == 0);
          if (desc ? (a < b) : (a > b)){ s[i] = b; s[ixj] = a; }
        }
      }
      __syncthreads();
    }
  }
  if (t < KJ){
    float jx = 1e6f, jy = 1e6f;
    if (t < count){
      unsigned idx = 0xFFFFFFFFu - (unsigned)(s[t] & 0xFFFFFFFFull);
      int yy = (int)(idx >> 7), xx = (int)(idx & 127u);
      jx = (float)xx + sigm(hm[7*HW + idx]);
      jy = (float)yy + sigm(hm[8*HW + idx]);
    }
    junc[2*t] = jx; junc[2*t+1] = jy;
  }
}

// ---------------- 4. junction-endpoint argmin matching ----------------
__global__ void k_match(const float* __restrict__ lines, const float* __restrict__ junc,
                        int* __restrict__ ids){
  __shared__ float jx[KJ], jy[KJ];
  int t = threadIdx.x;
  for (int k=t; k<KJ; k+=blockDim.x){ jx[k] = junc[2*k]; jy[k] = junc[2*k+1]; }
  __syncthreads();
  int n = blockIdx.x*blockDim.x + t;
  if (n >= NLINES) return;
  float4 L = ((const float4*)lines)[n];
  float b1 = 1e30f, b2 = 1e30f; int j1 = 0, j2 = 0;
  for (int k=0; k<KJ; k++){
    float dx1 = jx[k]-L.x, dy1 = jy[k]-L.y;
    float d1 = dx1*dx1 + dy1*dy1;
    float dx2 = jx[k]-L.z, dy2 = jy[k]-L.w;
    float d2 = dx2*dx2 + dy2*dy2;
    if (d1 < b1){ b1 = d1; j1 = k; }
    if (d2 < b2){ b2 = d2; j2 = k; }
  }
  int lo = min(j1,j2), hi = max(j1,j2);
  ids[n] = (lo < hi) ? (lo*KJ + hi) : SENT;
}

// ---------------- 5. sorted unique via bitmap + block scan ----------------
__global__ __launch_bounds__(1024) void k_unique(const int* __restrict__ ids,
    int* __restrict__ uid_list, int* __restrict__ mcount){
  __shared__ unsigned bm[BITWORDS];
  __shared__ int sums[1024];
  int t = threadIdx.x;
  for (int i=t; i<BITWORDS; i+=1024) bm[i] = 0u;
  __syncthreads();
  for (int n=t; n<NLINES; n+=1024){
    int id = ids[n];
    if (id < SENT) atomicOr(&bm[id>>5], 1u << (id & 31));
  }
  __syncthreads();
  int w0 = t*3;
  int local = 0;
  for (int w=w0; w<w0+3; w++) if (w < BITWORDS) local += __popc(bm[w]);
  sums[t] = local;
  __syncthreads();
  for (int off=1; off<1024; off<<=1){
    int v = sums[t];
    int add = (t >= off) ? sums[t-off] : 0;
    __syncthreads();
    sums[t] = v + add;
    __syncthreads();
  }
  int base = sums[t] - local;
  for (int w=w0; w<w0+3; w++){
    if (w >= BITWORDS) break;
    unsigned bits = bm[w];
    while (bits){
      int b = __ffs(bits) - 1;
      uid_list[base++] = w*32 + b;
      bits &= bits - 1;
    }
  }
  if (t == 1023) *mcount = sums[1023];
}

// ---------------- 6. line_coords output (+ zero scores past M) ----------------
__global__ void k_coords(const int* __restrict__ uid_list, const int* __restrict__ mcount,
                         const float* __restrict__ junc, float* __restrict__ out){
  int r = blockIdx.x*blockDim.x + threadIdx.x;
  if (r >= NLINES) return;
  int M = *mcount;
  float4 v = make_float4(0.f,0.f,0.f,0.f);
  if (r < M){
    int id = uid_list[r];
    int lo = id / KJ, hi = id % KJ;
    v = make_float4(junc[2*lo], junc[2*lo+1], junc[2*hi], junc[2*hi+1]);
  } else {
    out[4*NLINES + r] = 0.0f;
  }
  ((float4*)out)[r] = v;
}

// ---------------- 7. LOI feature map: [128,256]@[256,HW] -> pixel-major [HW][128] ----------------
#define LOI_TP 32
__global__ __launch_bounds__(256) void k_loi(const float* __restrict__ feat,
    const float* __restrict__ fc1w, const float* __restrict__ fc1b, float* __restrict__ loi){
  __shared__ float sf[256*LOI_TP];
  int p0 = blockIdx.x * LOI_TP;
  int t = threadIdx.x;
  for (int i=t; i<256*LOI_TP; i+=256){
    int c = i / LOI_TP, p = i % LOI_TP;
    sf[i] = feat[c*HW + p0 + p];
  }
  __syncthreads();
  int p = t & 31;
  int og = t >> 5;
  float acc[16];
  #pragma unroll
  for (int u=0; u<16; u++) acc[u] = 0.0f;
  for (int c=0; c<256; c++){
    float f = sf[c*LOI_TP + p];
    #pragma unroll
    for (int u=0; u<16; u++) acc[u] += fc1w[(og*16+u)*256 + c] * f;
  }
  float* dst = &loi[(size_t)(p0+p)*128 + og*16];
  #pragma unroll
  for (int u=0; u<16; u++) dst[u] = acc[u] + fc1b[og*16+u];
}

// ---------------- 8. weights fp32 -> bf16 ----------------
__global__ void k_cast(const float* __restrict__ w1, const float* __restrict__ w2,
                       short* __restrict__ w1b, short* __restrict__ w2b){
  int i = blockIdx.x*blockDim.x + threadIdx.x;
  if (i >= 1024*1024) return;
  w1b[i] = tobf(w1[i]);
  w2b[i] = tobf(w2[i]);
}

// ---------------- 9. per-line bilinear sampling + maxpool4 -> 1024 bf16 feats ----------------
__global__ __launch_bounds__(256) void k_sample(const float* __restrict__ out,
    const float* __restrict__ loi, const int* __restrict__ mcount,
    short* __restrict__ fbuf, float* __restrict__ logit, int chunk0, int chunk){
  int M = *mcount;
  int half = threadIdx.x >> 7;     // 2 rows per block
  int t = threadIdx.x & 127;       // channel
  for (int pb = blockIdx.x; pb*2 < chunk && chunk0 + pb*2 < M; pb += gridDim.x){
    int local = pb*2 + half;
    int r = chunk0 + local;
    if (r < M && local < chunk){
      if (t == 0) logit[local] = 0.0f;
      float4 C = ((const float4*)out)[r];
      float gmax[8];
      #pragma unroll
      for (int g=0; g<8; g++) gmax[g] = -1e30f;
      for (int s=0; s<32; s++){
        float tt = (float)s * (1.0f/31.0f);
        float px = C.x*tt + C.z*(1.0f-tt);
        float py = C.y*tt + C.w*(1.0f-tt);
        px = fminf(fmaxf(px, 0.0f), 127.0f);
        py = fminf(fmaxf(py, 0.0f), 127.0f);
        float x0 = floorf(px), y0 = floorf(py);
        int x0i = (int)x0, y0i = (int)y0;
        int x1i = min(x0i+1, 127), y1i = min(y0i+1, 127);
        float wx = px - x0, wy = py - y0;
        const float* p00 = loi + ((size_t)(y0i*WW + x0i))*128;
        const float* p01 = loi + ((size_t)(y0i*WW + x1i))*128;
        const float* p10 = loi + ((size_t)(y1i*WW + x0i))*128;
        const float* p11 = loi + ((size_t)(y1i*WW + x1i))*128;
        float v = p00[t]*(1.0f-wx)*(1.0f-wy) + p01[t]*wx*(1.0f-wy)
                + p10[t]*(1.0f-wx)*wy + p11[t]*wx*wy;
        gmax[s>>2] = fmaxf(gmax[s>>2], v);
      }
      bf16x8 pk;
      #pragma unroll
      for (int g=0; g<8; g++) pk[g] = tobf(gmax[g]);
      *(bf16x8*)&fbuf[(size_t)local*1024 + t*8] = pk;
    }
  }
}

// ---------------- 10. MFMA GEMM1: h1 = relu(f @ w1.T + b1), bf16 in, bf16 out ----------------
__global__ __launch_bounds__(256) void k_mlp1(const short* __restrict__ A,
    const short* __restrict__ W, const float* __restrict__ bias,
    short* __restrict__ H, const int* __restrict__ mcount, int chunk0){
  int M = *mcount;
  int rb = blockIdx.x * 64;
  if (chunk0 + rb >= M) return;
  int cb = blockIdx.y * 64;
  int lane = threadIdx.x & 63, wave = threadIdx.x >> 6;
  int l16 = lane & 15, quad = lane >> 4;
  const short* Ap = A + (size_t)(rb + wave*16 + l16)*1024 + quad*8;
  const short* Wp = W + (size_t)(cb + l16)*1024 + quad*8;
  f32x4 acc0 = {0,0,0,0}, acc1 = {0,0,0,0}, acc2 = {0,0,0,0}, acc3 = {0,0,0,0};
  #pragma unroll 4
  for (int k0=0; k0<1024; k0+=32){
    bf16x8 a  = *(const bf16x8*)(Ap + k0);
    bf16x8 b0 = *(const bf16x8*)(Wp + k0);
    bf16x8 b1 = *(const bf16x8*)(Wp + 16*1024 + k0);
    bf16x8 b2 = *(const bf16x8*)(Wp + 32*1024 + k0);
    bf16x8 b3 = *(const bf16x8*)(Wp + 48*1024 + k0);
    acc0 = __builtin_amdgcn_mfma_f32_16x16x32_bf16(a, b0, acc0, 0, 0, 0);
    acc1 = __builtin_amdgcn_mfma_f32_16x16x32_bf16(a, b1, acc1, 0, 0, 0);
    acc2 = __builtin_amdgcn_mfma_f32_16x16x32_bf16(a, b2, acc2, 0, 0, 0);
    acc3 = __builtin_amdgcn_mfma_f32_16x16x32_bf16(a, b3, acc3, 0, 0, 0);
  }
  int rowbase = rb + wave*16 + quad*4;
  int colbase = cb + l16;
  #pragma unroll
  for (int r=0; r<4; r++){
    size_t ro = (size_t)(rowbase + r)*1024;
    H[ro + colbase     ] = tobf(fmaxf(acc0[r] + bias[colbase     ], 0.0f));
    H[ro + colbase + 16] = tobf(fmaxf(acc1[r] + bias[colbase + 16], 0.0f));
    H[ro + colbase + 32] = tobf(fmaxf(acc2[r] + bias[colbase + 32], 0.0f));
    H[ro + colbase + 48] = tobf(fmaxf(acc3[r] + bias[colbase + 48], 0.0f));
  }
}

// ---------------- 11. MFMA GEMM2 + w3 dot fused -> logits ----------------
__global__ __launch_bounds__(256) void k_mlp2(const short* __restrict__ A,
    const short* __restrict__ W, const float* __restrict__ bias,
    const float* __restrict__ w3, float* __restrict__ logit,
    const int* __restrict__ mcount, int chunk0){
  int M = *mcount;
  int rb = blockIdx.x * 64;
  if (chunk0 + rb >= M) return;
  int cb = blockIdx.y * 64;
  int lane = threadIdx.x & 63, wave = threadIdx.x >> 6;
  int l16 = lane & 15, quad = lane >> 4;
  const short* Ap = A + (size_t)(rb + wave*16 + l16)*1024 + quad*8;
  const short* Wp = W + (size_t)(cb + l16)*1024 + quad*8;
  f32x4 acc0 = {0,0,0,0}, acc1 = {0,0,0,0}, acc2 = {0,0,0,0}, acc3 = {0,0,0,0};
  #pragma unroll 4
  for (int k0=0; k0<1024; k0+=32){
    bf16x8 a  = *(const bf16x8*)(Ap + k0);
    bf16x8 b0 = *(const bf16x8*)(Wp + k0);
    bf16x8 b1 = *(const bf16x8*)(Wp + 16*1024 + k0);
    bf16x8 b2 = *(const bf16x8*)(Wp + 32*1024 + k0);
    bf16x8 b3 = *(const bf16x8*)(Wp + 48*1024 + k0);
    acc0 = __builtin_amdgcn_mfma_f32_16x16x32_bf16(a, b0, acc0, 0, 0, 0);
    acc1 = __builtin_amdgcn_mfma_f32_16x16x32_bf16(a, b1, acc1, 0, 0, 0);
    acc2 = __builtin_amdgcn_mfma_f32_16x16x32_bf16(a, b2, acc2, 0, 0, 0);
    acc3 = __builtin_amdgcn_mfma_f32_16x16x32_bf16(a, b3, acc3, 0, 0, 0);
  }
  int rowbase = rb + wave*16 + quad*4;
  int colbase = cb + l16;
  float part[4];
  #pragma unroll
  for (int r=0; r<4; r++){
    float p = 0.0f;
    p += fmaxf(acc0[r] + bias[colbase     ], 0.0f) * w3[colbase     ];
    p += fmaxf(acc1[r] + bias[colbase + 16], 0.0f) * w3[colbase + 16];
    p += fmaxf(acc2[r] + bias[colbase + 32], 0.0f) * w3[colbase + 32];
    p += fmaxf(acc3[r] + bias[colbase + 48], 0.0f) * w3[colbase + 48];
    part[r] = p;
  }
  #pragma unroll
  for (int r=0; r<4; r++){
    #pragma unroll
    for (int m=1; m<16; m<<=1) part[r] += __shfl_xor(part[r], m, 16);
  }
  if (l16 == 0){
    #pragma unroll
    for (int r=0; r<4; r++) atomicAdd(&logit[rowbase + r], part[r]);
  }
}

// ---------------- 12. final sigmoid scores ----------------
__global__ void k_score(const float* __restrict__ logit, const float* __restrict__ b3,
                        const int* __restrict__ mcount, float* __restrict__ out, int chunk0){
  int i = blockIdx.x*blockDim.x + threadIdx.x;
  int r = chunk0 + i;
  if (r >= NLINES) return;
  int M = *mcount;
  if (r >= M) return;
  float lg = logit[i] + b3[0];
  out[4*NLINES + r] = 1.0f/(1.0f + expf(-lg));
}

extern "C" void kernel_launch(void* const* d_in, const int* in_sizes, int n_in,
                              void* d_out, int out_size, void* d_ws, size_t ws_size,
                              hipStream_t stream){
  const float* features = (const float*)d_in[0];
  const float* heatmaps = (const float*)d_in[1];
  const float* fc1_w    = (const float*)d_in[2];
  const float* fc1_b    = (const float*)d_in[3];
  const float* w1       = (const float*)d_in[4];
  const float* b1       = (const float*)d_in[5];
  const float* w2       = (const float*)d_in[6];
  const float* b2       = (const float*)d_in[7];
  const float* w3       = (const float*)d_in[8];
  const float* b3       = (const float*)d_in[9];
  float* out = (float*)d_out;

  char* ws = (char*)d_ws;
  size_t off = 0;
  auto alloc = [&](size_t bytes) -> void* {
    void* p = ws + off;
    off = (off + bytes + 255) & ~(size_t)255;
    return p;
  };
  float* jloc      = (float*)alloc(HW*4);
  float* lines     = (float*)alloc((size_t)NLINES*16);
  unsigned long long* cand = (unsigned long long*)alloc(CAND_CAP*8);
  int*   cand_count= (int*)alloc(4);
  float* junc      = (float*)alloc(KJ*2*4);
  int*   ids       = (int*)alloc((size_t)NLINES*4);
  int*   uid_list  = (int*)alloc((size_t)NLINES*4);
  int*   mcount    = (int*)alloc(4);
  float* loi       = (float*)alloc((size_t)HW*128*4);
  short* w1b       = (short*)alloc((size_t)1024*1024*2);
  short* w2b       = (short*)alloc((size_t)1024*1024*2);
  size_t fixed = off;

  // pick largest chunk that fits the workspace (constant across calls)
  const int chunk_opts[7] = {49152, 24576, 12288, 8192, 4096, 2048, 1024};
  int CHUNK = 1024;
  for (int ci=0; ci<7; ci++){
    size_t need = fixed + (size_t)chunk_opts[ci]*1024*2*2 + (size_t)chunk_opts[ci]*4 + 1024;
    if (need <= ws_size){ CHUNK = chunk_opts[ci]; break; }
  }
  short* fbuf  = (short*)alloc((size_t)CHUNK*1024*2);
  short* h1buf = (short*)alloc((size_t)CHUNK*1024*2);
  float* logit = (float*)alloc((size_t)CHUNK*4);

  k_prep <<<HW/256, 256, 0, stream>>>(heatmaps, jloc, lines, cand_count);
  k_nms  <<<HW/256, 256, 0, stream>>>(jloc, cand, cand_count);
  k_topk <<<1, 1024, 0, stream>>>(cand, cand_count, heatmaps, junc);
  k_match<<<NLINES/256, 256, 0, stream>>>(lines, junc, ids);
  k_unique<<<1, 1024, 0, stream>>>(ids, uid_list, mcount);
  k_coords<<<NLINES/256, 256, 0, stream>>>(uid_list, mcount, junc, out);
  k_loi  <<<HW/LOI_TP, 256, 0, stream>>>(features, fc1_w, fc1_b, loi);
  k_cast <<<(1024*1024)/256, 256, 0, stream>>>(w1, w2, w1b, w2b);

  int nchunk = NLINES / CHUNK;
  for (int ci=0; ci<nchunk; ci++){
    int chunk0 = ci * CHUNK;
    k_sample<<<512, 256, 0, stream>>>(out, loi, mcount, fbuf, logit, chunk0, CHUNK);
    dim3 g1(CHUNK/64, 16);
    k_mlp1<<<g1, 256, 0, stream>>>(fbuf, w1b, b1, h1buf, mcount, chunk0);
    k_mlp2<<<g1, 256, 0, stream>>>(h1buf, w2b, b2, w3, logit, mcount, chunk0);
    k_score<<<CHUNK/256, 256, 0, stream>>>(logit, b3, mcount, out, chunk0);
  }
}

// Round 3
// 259.166 us; speedup vs baseline: 2.8599x; 2.1867x over previous
//
#include <hip/hip_runtime.h>
#include <math.h>

#define HH 128
#define WW 128
#define HW 16384
#define NLINES 49152
#define KJ 300
#define SENT 90000
#define THRESHV 0.008f
#define CAND_CAP 8192
#define BITWORDS 2816

typedef __attribute__((ext_vector_type(8))) short bf16x8;
typedef __attribute__((ext_vector_type(4))) float f32x4;

__device__ __forceinline__ float sigm(float x){ return 1.0f/(1.0f+expf(-x)); }

__device__ __forceinline__ short tobf(float f){
  unsigned u = __float_as_uint(f);
  unsigned r = u + 0x7FFFu + ((u >> 16) & 1u);
  return (short)(r >> 16);
}

#define GLOAD_LDS16(g, l) \
  __builtin_amdgcn_global_load_lds((const __attribute__((address_space(1))) void*)(g), \
                                   (__attribute__((address_space(3))) void*)(l), 16, 0, 0)

// ---------------- 1. activations + HAFM line decode ----------------
__global__ void k_prep(const float* __restrict__ hm, float* __restrict__ jloc,
                       float* __restrict__ lines, int* __restrict__ cand_count){
  int i = blockIdx.x*blockDim.x + threadIdx.x;
  if (i == 0) *cand_count = 0;
  if (i >= HW) return;
  float h0 = hm[i], h1 = hm[HW+i], h2 = hm[2*HW+i], h3 = hm[3*HW+i], h4 = hm[4*HW+i];
  float h5 = hm[5*HW+i], h6 = hm[6*HW+i];
  float a0 = sigm(h0), a1 = sigm(h1), a2 = sigm(h2);
  float dist = sigm(h3), bias = sigm(h4);
  float mx = fmaxf(h5,h6);
  float e5 = expf(h5-mx), e6 = expf(h6-mx);
  jloc[i] = e6/(e5+e6);
  const float PI = 3.14159265358979323846f;
  float ang0 = (a0-0.5f)*(2.0f*PI);
  float c0 = cosf(ang0), s0 = sinf(ang0);
  float t1 = tanf(a1*(0.5f*PI));
  float t2 = tanf(-a2*(0.5f*PI));
  int y = i >> 7, x = i & 127;
  float fx = (float)x, fy = (float)y;
  #pragma unroll
  for (int c=0;c<3;c++){
    float d = fminf(fmaxf(dist + bias*(float)(c-1), 0.0f), 1.0f);
    float ds = d*5.0f;
    float x1 = fminf(fmaxf((c0 - s0*t1)*ds + fx, 0.0f), 127.0f);
    float y1 = fminf(fmaxf((s0 + c0*t1)*ds + fy, 0.0f), 127.0f);
    float x2 = fminf(fmaxf((c0 - s0*t2)*ds + fx, 0.0f), 127.0f);
    float y2 = fminf(fmaxf((s0 + c0*t2)*ds + fy, 0.0f), 127.0f);
    ((float4*)lines)[c*HW + i] = make_float4(x1,y1,x2,y2);
  }
}

// ---------------- 2. 3x3 NMS + compact candidates > THRESH ----------------
__global__ void k_nms(const float* __restrict__ jloc, unsigned long long* __restrict__ cand,
                      int* __restrict__ cand_count){
  int i = blockIdx.x*blockDim.x + threadIdx.x;
  if (i >= HW) return;
  int y = i >> 7, x = i & 127;
  float v = jloc[i];
  float m = v;
  for (int dy=-1; dy<=1; dy++){
    int ny = y + dy; if (ny < 0 || ny >= HH) continue;
    for (int dx=-1; dx<=1; dx++){
      int nx = x + dx; if (nx < 0 || nx >= WW) continue;
      m = fmaxf(m, jloc[ny*WW + nx]);
    }
  }
  if (v == m && v > THRESHV){
    int pos = atomicAdd(cand_count, 1);
    if (pos < CAND_CAP){
      unsigned int vb = __float_as_uint(v);
      cand[pos] = ((unsigned long long)vb << 32) | (unsigned long long)(0xFFFFFFFFu - (unsigned)i);
    }
  }
}

// ---------------- 3. single-block bitonic top-K (adaptive length) ----------------
__global__ __launch_bounds__(1024) void k_topk(const unsigned long long* __restrict__ cand,
    const int* __restrict__ cand_count, const float* __restrict__ hm, float* __restrict__ junc){
  __shared__ unsigned long long s[CAND_CAP];
  int t = threadIdx.x;
  int count = *cand_count; if (count > CAND_CAP) count = CAND_CAP;
  int n2 = 512;
  while (n2 < count) n2 <<= 1;
  for (int i=t; i<n2; i+=1024) s[i] = (i < count) ? cand[i] : 0ull;
  __syncthreads();
  for (int k=2; k<=n2; k<<=1){
    for (int j=k>>1; j>0; j>>=1){
      for (int i=t; i<n2; i+=1024){
        int ixj = i ^ j;
        if (ixj > i){
          unsigned long long a = s[i], b = s[ixj];
          bool desc = ((i & k) == 0);
          if (desc ? (a < b) : (a > b)){ s[i] = b; s[ixj] = a; }
        }
      }
      __syncthreads();
    }
  }
  if (t < KJ){
    float jx = 1e6f, jy = 1e6f;
    if (t < count){
      unsigned idx = 0xFFFFFFFFu - (unsigned)(s[t] & 0xFFFFFFFFull);
      int yy = (int)(idx >> 7), xx = (int)(idx & 127u);
      jx = (float)xx + sigm(hm[7*HW + idx]);
      jy = (float)yy + sigm(hm[8*HW + idx]);
    }
    junc[2*t] = jx; junc[2*t+1] = jy;
  }
}

// ---------------- 4. junction-endpoint argmin matching ----------------
__global__ void k_match(const float* __restrict__ lines, const float* __restrict__ junc,
                        int* __restrict__ ids){
  __shared__ float jx[KJ], jy[KJ];
  int t = threadIdx.x;
  for (int k=t; k<KJ; k+=blockDim.x){ jx[k] = junc[2*k]; jy[k] = junc[2*k+1]; }
  __syncthreads();
  int n = blockIdx.x*blockDim.x + t;
  if (n >= NLINES) return;
  float4 L = ((const float4*)lines)[n];
  float b1 = 1e30f, b2 = 1e30f; int j1 = 0, j2 = 0;
  for (int k=0; k<KJ; k++){
    float dx1 = jx[k]-L.x, dy1 = jy[k]-L.y;
    float d1 = dx1*dx1 + dy1*dy1;
    float dx2 = jx[k]-L.z, dy2 = jy[k]-L.w;
    float d2 = dx2*dx2 + dy2*dy2;
    if (d1 < b1){ b1 = d1; j1 = k; }
    if (d2 < b2){ b2 = d2; j2 = k; }
  }
  int lo = min(j1,j2), hi = max(j1,j2);
  ids[n] = (lo < hi) ? (lo*KJ + hi) : SENT;
}

// ---------------- 5. sorted unique via bitmap + block scan ----------------
__global__ __launch_bounds__(1024) void k_unique(const int* __restrict__ ids,
    int* __restrict__ uid_list, int* __restrict__ mcount){
  __shared__ unsigned bm[BITWORDS];
  __shared__ int sums[1024];
  int t = threadIdx.x;
  for (int i=t; i<BITWORDS; i+=1024) bm[i] = 0u;
  __syncthreads();
  for (int n=t; n<NLINES; n+=1024){
    int id = ids[n];
    if (id < SENT) atomicOr(&bm[id>>5], 1u << (id & 31));
  }
  __syncthreads();
  int w0 = t*3;
  int local = 0;
  for (int w=w0; w<w0+3; w++) if (w < BITWORDS) local += __popc(bm[w]);
  sums[t] = local;
  __syncthreads();
  for (int off=1; off<1024; off<<=1){
    int v = sums[t];
    int add = (t >= off) ? sums[t-off] : 0;
    __syncthreads();
    sums[t] = v + add;
    __syncthreads();
  }
  int base = sums[t] - local;
  for (int w=w0; w<w0+3; w++){
    if (w >= BITWORDS) break;
    unsigned bits = bm[w];
    while (bits){
      int b = __ffs(bits) - 1;
      uid_list[base++] = w*32 + b;
      bits &= bits - 1;
    }
  }
  if (t == 1023) *mcount = sums[1023];
}

// ---------------- 6. line_coords output (+ zero scores past M) ----------------
__global__ void k_coords(const int* __restrict__ uid_list, const int* __restrict__ mcount,
                         const float* __restrict__ junc, float* __restrict__ out){
  int r = blockIdx.x*blockDim.x + threadIdx.x;
  if (r >= NLINES) return;
  int M = *mcount;
  float4 v = make_float4(0.f,0.f,0.f,0.f);
  if (r < M){
    int id = uid_list[r];
    int lo = id / KJ, hi = id % KJ;
    v = make_float4(junc[2*lo], junc[2*lo+1], junc[2*hi], junc[2*hi+1]);
  } else {
    out[4*NLINES + r] = 0.0f;
  }
  ((float4*)out)[r] = v;
}

// ---------------- 7. transpose-cast features [256,HW] fp32 -> featT [HW,256] bf16 ----------------
__global__ __launch_bounds__(256) void k_tcast(const float* __restrict__ feat,
                                               short* __restrict__ featT){
  __shared__ float tile[32][33];
  int p0 = blockIdx.x * 32, c0 = blockIdx.y * 32;
  int tp = threadIdx.x & 31, tc = threadIdx.x >> 5;
  #pragma unroll
  for (int i=0; i<4; i++){
    int c = tc + i*8;
    tile[c][tp] = feat[(size_t)(c0 + c)*HW + p0 + tp];
  }
  __syncthreads();
  #pragma unroll
  for (int i=0; i<4; i++){
    int p = tc + i*8;
    featT[(size_t)(p0 + p)*256 + c0 + tp] = tobf(tile[tp][p]);
  }
}

// ---------------- 8. weights fp32 -> bf16 ----------------
__global__ void k_cast(const float* __restrict__ w1, const float* __restrict__ w2,
                       const float* __restrict__ fc1w,
                       short* __restrict__ w1b, short* __restrict__ w2b,
                       short* __restrict__ fc1b16){
  int i = blockIdx.x*blockDim.x + threadIdx.x;
  if (i >= 1024*1024) return;
  w1b[i] = tobf(w1[i]);
  w2b[i] = tobf(w2[i]);
  if (i < 128*256) fc1b16[i] = tobf(fc1w[i]);
}

// ---------------- 9. LDS-staged MFMA GEMM: C[64 x 128] per block ----------------
// A [rows,KDIM] bf16 row-major, B [cols,KDIM] bf16 row-major (B^T layout).
// MODE 0: Hout bf16 = relu(C + bias)     (layer 1)
// MODE 1: Fout fp32 = C + bias           (LOI feature map)
// MODE 2: logit += relu(C + bias) . w3   (layer 2, fused)
// XOR chunk swizzle: LDS[r][j] holds global 16B-chunk j^(r&7) of row r, so
// global_load_lds's fixed base+lane*16 layout still yields conflict-free
// ds_read_b128 MFMA frag reads (8 lanes per 4-bank group, uniform).
template<int KDIM, int MODE>
__global__ __launch_bounds__(256) void k_gemm(
    const short* __restrict__ A, const short* __restrict__ B,
    const float* __restrict__ bias, short* __restrict__ Hout,
    float* __restrict__ Fout, const float* __restrict__ w3,
    float* __restrict__ logit, const int* __restrict__ mcount,
    int chunk0, int ldc)
{
  int rb = blockIdx.x * 64;
  if (MODE != 1){
    int M = *mcount;
    if (chunk0 + rb >= M) return;
  }
  int cb = blockIdx.y * 128;
  __shared__ short As[64*64];    // 8 KB  [64 rows][8 chunks of 8 bf16]
  __shared__ short Bs[128*64];   // 16 KB
  int lane = threadIdx.x & 63, wave = threadIdx.x >> 6;
  int l16 = lane & 15, quad = lane >> 4;
  int srow = lane >> 3;              // 0..7
  int schunk = (lane & 7) ^ srow;    // swizzled source chunk

  f32x4 acc[8];
  #pragma unroll
  for (int g=0; g<8; g++) acc[g] = (f32x4){0,0,0,0};

  for (int k0=0; k0<KDIM; k0+=64){
    #pragma unroll
    for (int i=0; i<2; i++){
      int r0 = wave*16 + i*8;
      const short* g = A + (size_t)(rb + r0 + srow)*KDIM + k0 + schunk*8;
      GLOAD_LDS16(g, &As[r0*64]);
    }
    #pragma unroll
    for (int i=0; i<4; i++){
      int r0 = wave*32 + i*8;
      const short* g = B + (size_t)(cb + r0 + srow)*KDIM + k0 + schunk*8;
      GLOAD_LDS16(g, &Bs[r0*64]);
    }
    __syncthreads();
    #pragma unroll
    for (int s=0; s<2; s++){
      int slot = (s*4 + quad) ^ (l16 & 7);
      bf16x8 a = *(const bf16x8*)&As[(wave*16 + l16)*64 + slot*8];
      #pragma unroll
      for (int g=0; g<8; g++){
        bf16x8 b = *(const bf16x8*)&Bs[(g*16 + l16)*64 + slot*8];
        acc[g] = __builtin_amdgcn_mfma_f32_16x16x32_bf16(a, b, acc[g], 0, 0, 0);
      }
    }
    __syncthreads();
  }

  int rowbase = rb + wave*16 + quad*4;
  if (MODE == 0){
    #pragma unroll
    for (int g=0; g<8; g++){
      int col = cb + g*16 + l16;
      float bs = bias[col];
      #pragma unroll
      for (int r=0; r<4; r++)
        Hout[(size_t)(rowbase + r)*ldc + col] = tobf(fmaxf(acc[g][r] + bs, 0.0f));
    }
  } else if (MODE == 1){
    #pragma unroll
    for (int g=0; g<8; g++){
      int col = cb + g*16 + l16;
      float bs = bias[col];
      #pragma unroll
      for (int r=0; r<4; r++)
        Fout[(size_t)(rowbase + r)*ldc + col] = acc[g][r] + bs;
    }
  } else {
    float part[4] = {0.f,0.f,0.f,0.f};
    #pragma unroll
    for (int g=0; g<8; g++){
      int col = cb + g*16 + l16;
      float bs = bias[col], wv = w3[col];
      #pragma unroll
      for (int r=0; r<4; r++)
        part[r] += fmaxf(acc[g][r] + bs, 0.0f) * wv;
    }
    #pragma unroll
    for (int r=0; r<4; r++){
      #pragma unroll
      for (int m=1; m<16; m<<=1) part[r] += __shfl_xor(part[r], m, 16);
    }
    if (l16 == 0){
      #pragma unroll
      for (int r=0; r<4; r++) atomicAdd(&logit[rowbase + r], part[r]);
    }
  }
}

// ---------------- 10. per-line bilinear sampling + maxpool4 -> 1024 bf16 feats ----------------
__global__ __launch_bounds__(256) void k_sample(const float* __restrict__ out,
    const float* __restrict__ loi, const int* __restrict__ mcount,
    short* __restrict__ fbuf, float* __restrict__ logit, int chunk0, int chunk){
  int M = *mcount;
  int half = threadIdx.x >> 7;
  int t = threadIdx.x & 127;
  for (int pb = blockIdx.x; pb*2 < chunk && chunk0 + pb*2 < M; pb += gridDim.x){
    int local = pb*2 + half;
    int r = chunk0 + local;
    if (r < M && local < chunk){
      if (t == 0) logit[local] = 0.0f;
      float4 C = ((const float4*)out)[r];
      float gmax[8];
      #pragma unroll
      for (int g=0; g<8; g++) gmax[g] = -1e30f;
      for (int s=0; s<32; s++){
        float tt = (float)s * (1.0f/31.0f);
        float px = C.x*tt + C.z*(1.0f-tt);
        float py = C.y*tt + C.w*(1.0f-tt);
        px = fminf(fmaxf(px, 0.0f), 127.0f);
        py = fminf(fmaxf(py, 0.0f), 127.0f);
        float x0 = floorf(px), y0 = floorf(py);
        int x0i = (int)x0, y0i = (int)y0;
        int x1i = min(x0i+1, 127), y1i = min(y0i+1, 127);
        float wx = px - x0, wy = py - y0;
        const float* p00 = loi + ((size_t)(y0i*WW + x0i))*128;
        const float* p01 = loi + ((size_t)(y0i*WW + x1i))*128;
        const float* p10 = loi + ((size_t)(y1i*WW + x0i))*128;
        const float* p11 = loi + ((size_t)(y1i*WW + x1i))*128;
        float v = p00[t]*(1.0f-wx)*(1.0f-wy) + p01[t]*wx*(1.0f-wy)
                + p10[t]*(1.0f-wx)*wy + p11[t]*wx*wy;
        gmax[s>>2] = fmaxf(gmax[s>>2], v);
      }
      bf16x8 pk;
      #pragma unroll
      for (int g=0; g<8; g++) pk[g] = tobf(gmax[g]);
      *(bf16x8*)&fbuf[(size_t)local*1024 + t*8] = pk;
    }
  }
}

// ---------------- 11. final sigmoid scores ----------------
__global__ void k_score(const float* __restrict__ logit, const float* __restrict__ b3,
                        const int* __restrict__ mcount, float* __restrict__ out, int chunk0){
  int i = blockIdx.x*blockDim.x + threadIdx.x;
  int r = chunk0 + i;
  if (r >= NLINES) return;
  int M = *mcount;
  if (r >= M) return;
  float lg = logit[i] + b3[0];
  out[4*NLINES + r] = 1.0f/(1.0f + expf(-lg));
}

extern "C" void kernel_launch(void* const* d_in, const int* in_sizes, int n_in,
                              void* d_out, int out_size, void* d_ws, size_t ws_size,
                              hipStream_t stream){
  const float* features = (const float*)d_in[0];
  const float* heatmaps = (const float*)d_in[1];
  const float* fc1_w    = (const float*)d_in[2];
  const float* fc1_b    = (const float*)d_in[3];
  const float* w1       = (const float*)d_in[4];
  const float* b1       = (const float*)d_in[5];
  const float* w2       = (const float*)d_in[6];
  const float* b2       = (const float*)d_in[7];
  const float* w3       = (const float*)d_in[8];
  const float* b3       = (const float*)d_in[9];
  float* out = (float*)d_out;

  char* ws = (char*)d_ws;
  size_t off = 0;
  auto alloc = [&](size_t bytes) -> void* {
    void* p = ws + off;
    off = (off + bytes + 255) & ~(size_t)255;
    return p;
  };
  float* jloc      = (float*)alloc(HW*4);
  float* lines     = (float*)alloc((size_t)NLINES*16);
  unsigned long long* cand = (unsigned long long*)alloc(CAND_CAP*8);
  int*   cand_count= (int*)alloc(4);
  float* junc      = (float*)alloc(KJ*2*4);
  int*   ids       = (int*)alloc((size_t)NLINES*4);
  int*   uid_list  = (int*)alloc((size_t)NLINES*4);
  int*   mcount    = (int*)alloc(4);
  float* loi       = (float*)alloc((size_t)HW*128*4);
  short* featT     = (short*)alloc((size_t)HW*256*2);
  short* fc1b16    = (short*)alloc((size_t)128*256*2);
  short* w1b       = (short*)alloc((size_t)1024*1024*2);
  short* w2b       = (short*)alloc((size_t)1024*1024*2);
  size_t fixed = off;

  const int chunk_opts[7] = {49152, 24576, 12288, 8192, 4096, 2048, 1024};
  int CHUNK = 1024;
  for (int ci=0; ci<7; ci++){
    size_t need = fixed + (size_t)chunk_opts[ci]*1024*2*2 + (size_t)chunk_opts[ci]*4 + 1024;
    if (need <= ws_size){ CHUNK = chunk_opts[ci]; break; }
  }
  short* fbuf  = (short*)alloc((size_t)CHUNK*1024*2);
  short* h1buf = (short*)alloc((size_t)CHUNK*1024*2);
  float* logit = (float*)alloc((size_t)CHUNK*4);

  k_prep <<<HW/256, 256, 0, stream>>>(heatmaps, jloc, lines, cand_count);
  k_nms  <<<HW/256, 256, 0, stream>>>(jloc, cand, cand_count);
  k_tcast<<<dim3(HW/32, 8), 256, 0, stream>>>(features, featT);
  k_cast <<<(1024*1024)/256, 256, 0, stream>>>(w1, w2, fc1_w, w1b, w2b, fc1b16);
  k_topk <<<1, 1024, 0, stream>>>(cand, cand_count, heatmaps, junc);
  // LOI GEMM: [HW,256] @ [128,256]^T -> loi [HW,128] fp32
  k_gemm<256,1><<<dim3(HW/64, 1), 256, 0, stream>>>(
      featT, fc1b16, fc1_b, nullptr, loi, nullptr, nullptr, nullptr, 0, 128);
  k_match<<<NLINES/256, 256, 0, stream>>>(lines, junc, ids);
  k_unique<<<1, 1024, 0, stream>>>(ids, uid_list, mcount);
  k_coords<<<NLINES/256, 256, 0, stream>>>(uid_list, mcount, junc, out);

  int nchunk = NLINES / CHUNK;
  for (int ci=0; ci<nchunk; ci++){
    int chunk0 = ci * CHUNK;
    k_sample<<<512, 256, 0, stream>>>(out, loi, mcount, fbuf, logit, chunk0, CHUNK);
    dim3 g1(CHUNK/64, 8);
    k_gemm<1024,0><<<g1, 256, 0, stream>>>(
        fbuf, w1b, b1, h1buf, nullptr, nullptr, nullptr, mcount, chunk0, 1024);
    k_gemm<1024,2><<<g1, 256, 0, stream>>>(
        h1buf, w2b, b2, nullptr, nullptr, w3, logit, mcount, chunk0, 1024);
    k_score<<<CHUNK/256, 256, 0, stream>>>(logit, b3, mcount, out, chunk0);
  }
}

// Round 4
// 230.143 us; speedup vs baseline: 3.2205x; 1.1261x over previous
//
#include <hip/hip_runtime.h>
#include <math.h>

#define HH 128
#define WW 128
#define HW 16384
#define NLINES 49152
#define KJ 300
#define SENT 90000
#define THRESHV 0.008f
#define CAND_CAP 8192
#define BITWORDS 2816

typedef __attribute__((ext_vector_type(8))) short bf16x8;
typedef __attribute__((ext_vector_type(4))) float f32x4;

__device__ __forceinline__ float sigm(float x){ return 1.0f/(1.0f+expf(-x)); }

__device__ __forceinline__ short tobf(float f){
  unsigned u = __float_as_uint(f);
  unsigned r = u + 0x7FFFu + ((u >> 16) & 1u);
  return (short)(r >> 16);
}
__device__ __forceinline__ float bflo(unsigned u){ return __uint_as_float(u << 16); }
__device__ __forceinline__ float bfhi(unsigned u){ return __uint_as_float(u & 0xFFFF0000u); }

#define GLOAD_LDS16(g, l) \
  __builtin_amdgcn_global_load_lds((const __attribute__((address_space(1))) void*)(g), \
                                   (__attribute__((address_space(3))) void*)(l), 16, 0, 0)

// ---------------- 1. HAFM line decode (+ cand_count init) ----------------
__global__ void k_prep(const float* __restrict__ hm, float* __restrict__ lines,
                       int* __restrict__ cand_count){
  int i = blockIdx.x*blockDim.x + threadIdx.x;
  if (i == 0) *cand_count = 0;
  if (i >= HW) return;
  float h0 = hm[i], h1 = hm[HW+i], h2 = hm[2*HW+i], h3 = hm[3*HW+i], h4 = hm[4*HW+i];
  float a0 = sigm(h0), a1 = sigm(h1), a2 = sigm(h2);
  float dist = sigm(h3), bias = sigm(h4);
  const float PI = 3.14159265358979323846f;
  float ang0 = (a0-0.5f)*(2.0f*PI);
  float c0 = cosf(ang0), s0 = sinf(ang0);
  float t1 = tanf(a1*(0.5f*PI));
  float t2 = tanf(-a2*(0.5f*PI));
  int y = i >> 7, x = i & 127;
  float fx = (float)x, fy = (float)y;
  #pragma unroll
  for (int c=0;c<3;c++){
    float d = fminf(fmaxf(dist + bias*(float)(c-1), 0.0f), 1.0f);
    float ds = d*5.0f;
    float x1 = fminf(fmaxf((c0 - s0*t1)*ds + fx, 0.0f), 127.0f);
    float y1 = fminf(fmaxf((s0 + c0*t1)*ds + fy, 0.0f), 127.0f);
    float x2 = fminf(fmaxf((c0 - s0*t2)*ds + fx, 0.0f), 127.0f);
    float y2 = fminf(fmaxf((s0 + c0*t2)*ds + fy, 0.0f), 127.0f);
    ((float4*)lines)[c*HW + i] = make_float4(x1,y1,x2,y2);
  }
}

// ---------------- 2. fused softmax + 3x3 NMS + compact candidates ----------------
__device__ __forceinline__ float jloc_at(const float* hm, int idx){
  float h5 = hm[5*HW + idx], h6 = hm[6*HW + idx];
  float mx = fmaxf(h5,h6);
  float e5 = expf(h5-mx), e6 = expf(h6-mx);
  return e6/(e5+e6);
}
__global__ void k_nms(const float* __restrict__ hm, unsigned long long* __restrict__ cand,
                      int* __restrict__ cand_count){
  int i = blockIdx.x*blockDim.x + threadIdx.x;
  if (i >= HW) return;
  int y = i >> 7, x = i & 127;
  float v = jloc_at(hm, i);
  float m = v;
  for (int dy=-1; dy<=1; dy++){
    int ny = y + dy; if (ny < 0 || ny >= HH) continue;
    for (int dx=-1; dx<=1; dx++){
      int nx = x + dx; if (nx < 0 || nx >= WW) continue;
      m = fmaxf(m, jloc_at(hm, ny*WW + nx));
    }
  }
  if (v == m && v > THRESHV){
    int pos = atomicAdd(cand_count, 1);
    if (pos < CAND_CAP){
      unsigned int vb = __float_as_uint(v);
      cand[pos] = ((unsigned long long)vb << 32) | (unsigned long long)(0xFFFFFFFFu - (unsigned)i);
    }
  }
}

// ---------------- 3. single-block bitonic top-K (adaptive length) ----------------
__global__ __launch_bounds__(1024) void k_topk(const unsigned long long* __restrict__ cand,
    const int* __restrict__ cand_count, const float* __restrict__ hm, float* __restrict__ junc){
  __shared__ unsigned long long s[CAND_CAP];
  int t = threadIdx.x;
  int count = *cand_count; if (count > CAND_CAP) count = CAND_CAP;
  int n2 = 512;
  while (n2 < count) n2 <<= 1;
  for (int i=t; i<n2; i+=1024) s[i] = (i < count) ? cand[i] : 0ull;
  __syncthreads();
  for (int k=2; k<=n2; k<<=1){
    for (int j=k>>1; j>0; j>>=1){
      for (int i=t; i<n2; i+=1024){
        int ixj = i ^ j;
        if (ixj > i){
          unsigned long long a = s[i], b = s[ixj];
          bool desc = ((i & k) == 0);
          if (desc ? (a < b) : (a > b)){ s[i] = b; s[ixj] = a; }
        }
      }
      __syncthreads();
    }
  }
  if (t < KJ){
    float jx = 1e6f, jy = 1e6f;
    if (t < count){
      unsigned idx = 0xFFFFFFFFu - (unsigned)(s[t] & 0xFFFFFFFFull);
      int yy = (int)(idx >> 7), xx = (int)(idx & 127u);
      jx = (float)xx + sigm(hm[7*HW + idx]);
      jy = (float)yy + sigm(hm[8*HW + idx]);
    }
    junc[2*t] = jx; junc[2*t+1] = jy;
  }
}

// ---------------- 4. junction-endpoint argmin matching ----------------
__global__ void k_match(const float* __restrict__ lines, const float* __restrict__ junc,
                        int* __restrict__ ids){
  __shared__ float jx[KJ], jy[KJ];
  int t = threadIdx.x;
  for (int k=t; k<KJ; k+=blockDim.x){ jx[k] = junc[2*k]; jy[k] = junc[2*k+1]; }
  __syncthreads();
  int n = blockIdx.x*blockDim.x + t;
  if (n >= NLINES) return;
  float4 L = ((const float4*)lines)[n];
  float b1 = 1e30f, b2 = 1e30f; int j1 = 0, j2 = 0;
  for (int k=0; k<KJ; k++){
    float dx1 = jx[k]-L.x, dy1 = jy[k]-L.y;
    float d1 = dx1*dx1 + dy1*dy1;
    float dx2 = jx[k]-L.z, dy2 = jy[k]-L.w;
    float d2 = dx2*dx2 + dy2*dy2;
    if (d1 < b1){ b1 = d1; j1 = k; }
    if (d2 < b2){ b2 = d2; j2 = k; }
  }
  int lo = min(j1,j2), hi = max(j1,j2);
  ids[n] = (lo < hi) ? (lo*KJ + hi) : SENT;
}

// ---------------- 5. sorted unique via bitmap + block scan ----------------
__global__ __launch_bounds__(1024) void k_unique(const int* __restrict__ ids,
    int* __restrict__ uid_list, int* __restrict__ mcount){
  __shared__ unsigned bm[BITWORDS];
  __shared__ int sums[1024];
  int t = threadIdx.x;
  for (int i=t; i<BITWORDS; i+=1024) bm[i] = 0u;
  __syncthreads();
  for (int n=t; n<NLINES; n+=1024){
    int id = ids[n];
    if (id < SENT) atomicOr(&bm[id>>5], 1u << (id & 31));
  }
  __syncthreads();
  int w0 = t*3;
  int local = 0;
  for (int w=w0; w<w0+3; w++) if (w < BITWORDS) local += __popc(bm[w]);
  sums[t] = local;
  __syncthreads();
  for (int off=1; off<1024; off<<=1){
    int v = sums[t];
    int add = (t >= off) ? sums[t-off] : 0;
    __syncthreads();
    sums[t] = v + add;
    __syncthreads();
  }
  int base = sums[t] - local;
  for (int w=w0; w<w0+3; w++){
    if (w >= BITWORDS) break;
    unsigned bits = bm[w];
    while (bits){
      int b = __ffs(bits) - 1;
      uid_list[base++] = w*32 + b;
      bits &= bits - 1;
    }
  }
  if (t == 1023) *mcount = sums[1023];
}

// ---------------- 6. line_coords output (+ zero scores past M) ----------------
__global__ void k_coords(const int* __restrict__ uid_list, const int* __restrict__ mcount,
                         const float* __restrict__ junc, float* __restrict__ out){
  int r = blockIdx.x*blockDim.x + threadIdx.x;
  if (r >= NLINES) return;
  int M = *mcount;
  float4 v = make_float4(0.f,0.f,0.f,0.f);
  if (r < M){
    int id = uid_list[r];
    int lo = id / KJ, hi = id % KJ;
    v = make_float4(junc[2*lo], junc[2*lo+1], junc[2*hi], junc[2*hi+1]);
  } else {
    out[4*NLINES + r] = 0.0f;
  }
  ((float4*)out)[r] = v;
}

// ---------------- 7. transpose-cast features [256,HW] fp32 -> featT [HW,256] bf16 ----------------
__global__ __launch_bounds__(256) void k_tcast(const float* __restrict__ feat,
                                               short* __restrict__ featT){
  __shared__ float tile[32][33];
  int p0 = blockIdx.x * 32, c0 = blockIdx.y * 32;
  int tp = threadIdx.x & 31, tc = threadIdx.x >> 5;
  #pragma unroll
  for (int i=0; i<4; i++){
    int c = tc + i*8;
    tile[c][tp] = feat[(size_t)(c0 + c)*HW + p0 + tp];
  }
  __syncthreads();
  #pragma unroll
  for (int i=0; i<4; i++){
    int p = tc + i*8;
    featT[(size_t)(p0 + p)*256 + c0 + tp] = tobf(tile[tp][p]);
  }
}

// ---------------- 8. weights fp32 -> bf16 ----------------
__global__ void k_cast(const float* __restrict__ w1, const float* __restrict__ w2,
                       const float* __restrict__ fc1w,
                       short* __restrict__ w1b, short* __restrict__ w2b,
                       short* __restrict__ fc1b16){
  int i = blockIdx.x*blockDim.x + threadIdx.x;
  if (i >= 1024*1024) return;
  w1b[i] = tobf(w1[i]);
  w2b[i] = tobf(w2[i]);
  if (i < 128*256) fc1b16[i] = tobf(fc1w[i]);
}

// ---------------- 9. LDS-staged MFMA GEMM: C[64 x 128] per block ----------------
// A [rows,KDIM] bf16 row-major, B [cols,KDIM] bf16 row-major (B^T layout).
// MODE 0: Hout bf16 = relu(C + bias)     (layer 1)
// MODE 1: Hout bf16 = C + bias, no mcount gate (LOI feature map)
// MODE 2: logit += relu(C + bias) . w3   (layer 2, fused)
template<int KDIM, int MODE>
__global__ __launch_bounds__(256) void k_gemm(
    const short* __restrict__ A, const short* __restrict__ B,
    const float* __restrict__ bias, short* __restrict__ Hout,
    const float* __restrict__ w3, float* __restrict__ logit,
    const int* __restrict__ mcount, int chunk0, int ldc)
{
  int rb = blockIdx.x * 64;
  if (MODE != 1){
    int M = *mcount;
    if (chunk0 + rb >= M) return;
  }
  int cb = blockIdx.y * 128;
  __shared__ short As[64*64];
  __shared__ short Bs[128*64];
  int lane = threadIdx.x & 63, wave = threadIdx.x >> 6;
  int l16 = lane & 15, quad = lane >> 4;
  int srow = lane >> 3;
  int schunk = (lane & 7) ^ srow;

  f32x4 acc[8];
  #pragma unroll
  for (int g=0; g<8; g++) acc[g] = (f32x4){0,0,0,0};

  for (int k0=0; k0<KDIM; k0+=64){
    #pragma unroll
    for (int i=0; i<2; i++){
      int r0 = wave*16 + i*8;
      const short* g = A + (size_t)(rb + r0 + srow)*KDIM + k0 + schunk*8;
      GLOAD_LDS16(g, &As[r0*64]);
    }
    #pragma unroll
    for (int i=0; i<4; i++){
      int r0 = wave*32 + i*8;
      const short* g = B + (size_t)(cb + r0 + srow)*KDIM + k0 + schunk*8;
      GLOAD_LDS16(g, &Bs[r0*64]);
    }
    __syncthreads();
    #pragma unroll
    for (int s=0; s<2; s++){
      int slot = (s*4 + quad) ^ (l16 & 7);
      bf16x8 a = *(const bf16x8*)&As[(wave*16 + l16)*64 + slot*8];
      #pragma unroll
      for (int g=0; g<8; g++){
        bf16x8 b = *(const bf16x8*)&Bs[(g*16 + l16)*64 + slot*8];
        acc[g] = __builtin_amdgcn_mfma_f32_16x16x32_bf16(a, b, acc[g], 0, 0, 0);
      }
    }
    __syncthreads();
  }

  int rowbase = rb + wave*16 + quad*4;
  if (MODE == 0){
    #pragma unroll
    for (int g=0; g<8; g++){
      int col = cb + g*16 + l16;
      float bs = bias[col];
      #pragma unroll
      for (int r=0; r<4; r++)
        Hout[(size_t)(rowbase + r)*ldc + col] = tobf(fmaxf(acc[g][r] + bs, 0.0f));
    }
  } else if (MODE == 1){
    #pragma unroll
    for (int g=0; g<8; g++){
      int col = cb + g*16 + l16;
      float bs = bias[col];
      #pragma unroll
      for (int r=0; r<4; r++)
        Hout[(size_t)(rowbase + r)*ldc + col] = tobf(acc[g][r] + bs);
    }
  } else {
    float part[4] = {0.f,0.f,0.f,0.f};
    #pragma unroll
    for (int g=0; g<8; g++){
      int col = cb + g*16 + l16;
      float bs = bias[col], wv = w3[col];
      #pragma unroll
      for (int r=0; r<4; r++)
        part[r] += fmaxf(acc[g][r] + bs, 0.0f) * wv;
    }
    #pragma unroll
    for (int r=0; r<4; r++){
      #pragma unroll
      for (int m=1; m<16; m<<=1) part[r] += __shfl_xor(part[r], m, 16);
    }
    if (l16 == 0){
      #pragma unroll
      for (int r=0; r<4; r++) atomicAdd(&logit[rowbase + r], part[r]);
    }
  }
}

// ---------------- 10. sampling: phase-A shared step params, phase-B 2ch/thread ----------------
// loi is bf16 [HW][128]. Block handles one line per grid-stride iteration.
__global__ __launch_bounds__(256) void k_sample(const float* __restrict__ out,
    const short* __restrict__ loi, const int* __restrict__ mcount,
    short* __restrict__ fbuf, float* __restrict__ logit, int chunk0, int chunk){
  __shared__ int4   sOffs[32];
  __shared__ float4 sWts[32];
  int M = *mcount;
  int t = threadIdx.x;
  int q  = t >> 6;            // step-quarter 0..3 (uniform per wave)
  int c2 = (t & 63) << 1;     // channel pair
  for (int l = blockIdx.x; l < chunk && chunk0 + l < M; l += gridDim.x){
    int r = chunk0 + l;
    if (t == 0) logit[l] = 0.0f;
    __syncthreads();          // protect LDS from previous iteration's readers
    if (t < 32){
      float4 C = ((const float4*)out)[r];
      float tt = (float)t * (1.0f/31.0f);
      float px = C.x*tt + C.z*(1.0f-tt);
      float py = C.y*tt + C.w*(1.0f-tt);
      px = fminf(fmaxf(px, 0.0f), 127.0f);
      py = fminf(fmaxf(py, 0.0f), 127.0f);
      float x0 = floorf(px), y0 = floorf(py);
      int x0i = (int)x0, y0i = (int)y0;
      int x1i = min(x0i+1, 127), y1i = min(y0i+1, 127);
      float wx = px - x0, wy = py - y0;
      sOffs[t] = make_int4((y0i*WW + x0i)*128, (y0i*WW + x1i)*128,
                           (y1i*WW + x0i)*128, (y1i*WW + x1i)*128);
      sWts[t]  = make_float4((1.0f-wx)*(1.0f-wy), wx*(1.0f-wy),
                             (1.0f-wx)*wy,        wx*wy);
    }
    __syncthreads();
    float gl0=-1e30f, gl1=-1e30f, gh0=-1e30f, gh1=-1e30f;
    #pragma unroll
    for (int j=0; j<8; j++){
      int s = q*8 + j;
      int4 o   = sOffs[s];
      float4 w = sWts[s];
      unsigned u00 = *(const unsigned*)&loi[o.x + c2];
      unsigned u01 = *(const unsigned*)&loi[o.y + c2];
      unsigned u10 = *(const unsigned*)&loi[o.z + c2];
      unsigned u11 = *(const unsigned*)&loi[o.w + c2];
      float vlo = w.x*bflo(u00) + w.y*bflo(u01) + w.z*bflo(u10) + w.w*bflo(u11);
      float vhi = w.x*bfhi(u00) + w.y*bfhi(u01) + w.z*bfhi(u10) + w.w*bfhi(u11);
      if (j < 4){ gl0 = fmaxf(gl0, vlo); gh0 = fmaxf(gh0, vhi); }
      else      { gl1 = fmaxf(gl1, vlo); gh1 = fmaxf(gh1, vhi); }
    }
    unsigned plo = ((unsigned)(unsigned short)tobf(gl0)) | (((unsigned)(unsigned short)tobf(gl1)) << 16);
    unsigned phi = ((unsigned)(unsigned short)tobf(gh0)) | (((unsigned)(unsigned short)tobf(gh1)) << 16);
    *(unsigned*)&fbuf[(size_t)l*1024 + c2*8 + q*2]     = plo;
    *(unsigned*)&fbuf[(size_t)l*1024 + (c2+1)*8 + q*2] = phi;
  }
}

// ---------------- 11. final sigmoid scores ----------------
__global__ void k_score(const float* __restrict__ logit, const float* __restrict__ b3,
                        const int* __restrict__ mcount, float* __restrict__ out, int chunk0){
  int i = blockIdx.x*blockDim.x + threadIdx.x;
  int r = chunk0 + i;
  if (r >= NLINES) return;
  int M = *mcount;
  if (r >= M) return;
  float lg = logit[i] + b3[0];
  out[4*NLINES + r] = 1.0f/(1.0f + expf(-lg));
}

extern "C" void kernel_launch(void* const* d_in, const int* in_sizes, int n_in,
                              void* d_out, int out_size, void* d_ws, size_t ws_size,
                              hipStream_t stream){
  const float* features = (const float*)d_in[0];
  const float* heatmaps = (const float*)d_in[1];
  const float* fc1_w    = (const float*)d_in[2];
  const float* fc1_b    = (const float*)d_in[3];
  const float* w1       = (const float*)d_in[4];
  const float* b1       = (const float*)d_in[5];
  const float* w2       = (const float*)d_in[6];
  const float* b2       = (const float*)d_in[7];
  const float* w3       = (const float*)d_in[8];
  const float* b3       = (const float*)d_in[9];
  float* out = (float*)d_out;

  char* ws = (char*)d_ws;
  size_t off = 0;
  auto alloc = [&](size_t bytes) -> void* {
    void* p = ws + off;
    off = (off + bytes + 255) & ~(size_t)255;
    return p;
  };
  float* lines     = (float*)alloc((size_t)NLINES*16);
  unsigned long long* cand = (unsigned long long*)alloc(CAND_CAP*8);
  int*   cand_count= (int*)alloc(4);
  float* junc      = (float*)alloc(KJ*2*4);
  int*   ids       = (int*)alloc((size_t)NLINES*4);
  int*   uid_list  = (int*)alloc((size_t)NLINES*4);
  int*   mcount    = (int*)alloc(4);
  short* loi       = (short*)alloc((size_t)HW*128*2);
  short* featT     = (short*)alloc((size_t)HW*256*2);
  short* fc1b16    = (short*)alloc((size_t)128*256*2);
  short* w1b       = (short*)alloc((size_t)1024*1024*2);
  short* w2b       = (short*)alloc((size_t)1024*1024*2);
  size_t fixed = off;

  const int chunk_opts[7] = {49152, 24576, 12288, 8192, 4096, 2048, 1024};
  int CHUNK = 1024;
  for (int ci=0; ci<7; ci++){
    size_t need = fixed + (size_t)chunk_opts[ci]*1024*2*2 + (size_t)chunk_opts[ci]*4 + 1024;
    if (need <= ws_size){ CHUNK = chunk_opts[ci]; break; }
  }
  short* fbuf  = (short*)alloc((size_t)CHUNK*1024*2);
  short* h1buf = (short*)alloc((size_t)CHUNK*1024*2);
  float* logit = (float*)alloc((size_t)CHUNK*4);

  k_prep <<<HW/256, 256, 0, stream>>>(heatmaps, lines, cand_count);
  k_nms  <<<HW/256, 256, 0, stream>>>(heatmaps, cand, cand_count);
  k_tcast<<<dim3(HW/32, 8), 256, 0, stream>>>(features, featT);
  k_cast <<<(1024*1024)/256, 256, 0, stream>>>(w1, w2, fc1_w, w1b, w2b, fc1b16);
  k_topk <<<1, 1024, 0, stream>>>(cand, cand_count, heatmaps, junc);
  // LOI GEMM: [HW,256] @ [128,256]^T -> loi [HW,128] bf16
  k_gemm<256,1><<<dim3(HW/64, 1), 256, 0, stream>>>(
      featT, fc1b16, fc1_b, loi, nullptr, nullptr, nullptr, 0, 128);
  k_match<<<NLINES/256, 256, 0, stream>>>(lines, junc, ids);
  k_unique<<<1, 1024, 0, stream>>>(ids, uid_list, mcount);
  k_coords<<<NLINES/256, 256, 0, stream>>>(uid_list, mcount, junc, out);

  int nchunk = NLINES / CHUNK;
  for (int ci=0; ci<nchunk; ci++){
    int chunk0 = ci * CHUNK;
    k_sample<<<2048, 256, 0, stream>>>(out, loi, mcount, fbuf, logit, chunk0, CHUNK);
    dim3 g1(CHUNK/64, 8);
    k_gemm<1024,0><<<g1, 256, 0, stream>>>(
        fbuf, w1b, b1, h1buf, nullptr, nullptr, mcount, chunk0, 1024);
    k_gemm<1024,2><<<g1, 256, 0, stream>>>(
        h1buf, w2b, b2, nullptr, w3, logit, mcount, chunk0, 1024);
    k_score<<<CHUNK/256, 256, 0, stream>>>(logit, b3, mcount, out, chunk0);
  }
}

// Round 5
// 224.146 us; speedup vs baseline: 3.3067x; 1.0268x over previous
//
#include <hip/hip_runtime.h>
#include <math.h>

#define HH 128
#define WW 128
#define HW 16384
#define NLINES 49152
#define KJ 300
#define SENT 90000
#define THRESHV 0.008f
#define CAND_CAP 4096
#define BITWORDS 2816

typedef __attribute__((ext_vector_type(8))) short bf16x8;
typedef __attribute__((ext_vector_type(4))) float f32x4;

__device__ __forceinline__ float sigm(float x){ return 1.0f/(1.0f+expf(-x)); }

__device__ __forceinline__ short tobf(float f){
  unsigned u = __float_as_uint(f);
  unsigned r = u + 0x7FFFu + ((u >> 16) & 1u);
  return (short)(r >> 16);
}
__device__ __forceinline__ float bflo(unsigned u){ return __uint_as_float(u << 16); }
__device__ __forceinline__ float bfhi(unsigned u){ return __uint_as_float(u & 0xFFFF0000u); }

#define GLOAD_LDS16(g, l) \
  __builtin_amdgcn_global_load_lds((const __attribute__((address_space(1))) void*)(g), \
                                   (__attribute__((address_space(3))) void*)(l), 16, 0, 0)

// ---------------- 1. fused front: prep+nms | feature transpose-cast | fc1 cast ----
__device__ __forceinline__ float jloc_at(const float* hm, int idx){
  float h5 = hm[5*HW + idx], h6 = hm[6*HW + idx];
  float mx = fmaxf(h5,h6);
  float e5 = expf(h5-mx), e6 = expf(h6-mx);
  return e6/(e5+e6);
}

__global__ __launch_bounds__(256) void k_front(const float* __restrict__ hm,
    const float* __restrict__ feat, const float* __restrict__ fc1w,
    float* __restrict__ lines, unsigned long long* __restrict__ cand,
    int* __restrict__ cand_count, short* __restrict__ featT, short* __restrict__ fc1b16){
  __shared__ float tile[32][33];
  int b = blockIdx.x, t = threadIdx.x;
  if (b < 64){
    // ---- prep + nms (one pixel per thread) ----
    int i = b*256 + t;
    float h0 = hm[i], h1 = hm[HW+i], h2 = hm[2*HW+i], h3 = hm[3*HW+i], h4 = hm[4*HW+i];
    float a0 = sigm(h0), a1 = sigm(h1), a2 = sigm(h2);
    float dist = sigm(h3), bias = sigm(h4);
    const float PI = 3.14159265358979323846f;
    float ang0 = (a0-0.5f)*(2.0f*PI);
    float c0 = cosf(ang0), s0 = sinf(ang0);
    float t1 = tanf(a1*(0.5f*PI));
    float t2 = tanf(-a2*(0.5f*PI));
    int y = i >> 7, x = i & 127;
    float fx = (float)x, fy = (float)y;
    #pragma unroll
    for (int c=0;c<3;c++){
      float d = fminf(fmaxf(dist + bias*(float)(c-1), 0.0f), 1.0f);
      float ds = d*5.0f;
      float x1 = fminf(fmaxf((c0 - s0*t1)*ds + fx, 0.0f), 127.0f);
      float y1 = fminf(fmaxf((s0 + c0*t1)*ds + fy, 0.0f), 127.0f);
      float x2 = fminf(fmaxf((c0 - s0*t2)*ds + fx, 0.0f), 127.0f);
      float y2 = fminf(fmaxf((s0 + c0*t2)*ds + fy, 0.0f), 127.0f);
      ((float4*)lines)[c*HW + i] = make_float4(x1,y1,x2,y2);
    }
    float v = jloc_at(hm, i);
    float m = v;
    for (int dy=-1; dy<=1; dy++){
      int ny = y + dy; if (ny < 0 || ny >= HH) continue;
      for (int dx=-1; dx<=1; dx++){
        int nx = x + dx; if (nx < 0 || nx >= WW) continue;
        m = fmaxf(m, jloc_at(hm, ny*WW + nx));
      }
    }
    if (v == m && v > THRESHV){
      int pos = atomicAdd(cand_count, 1);
      if (pos < CAND_CAP){
        unsigned int vb = __float_as_uint(v);
        cand[pos] = ((unsigned long long)vb << 32) | (unsigned long long)(0xFFFFFFFFu - (unsigned)i);
      }
    }
  } else if (b < 64 + 4096){
    // ---- transpose-cast features [256,HW] fp32 -> featT [HW,256] bf16 ----
    int idx = b - 64;
    int p0 = (idx & 511) * 32, c0 = (idx >> 9) * 32;
    int tp = t & 31, tc = t >> 5;
    #pragma unroll
    for (int i=0; i<4; i++){
      int c = tc + i*8;
      tile[c][tp] = feat[(size_t)(c0 + c)*HW + p0 + tp];
    }
    __syncthreads();
    #pragma unroll
    for (int i=0; i<4; i++){
      int p = tc + i*8;
      featT[(size_t)(p0 + p)*256 + c0 + tp] = tobf(tile[tp][p]);
    }
  } else {
    int j = (b - 4160)*256 + t;   // < 32768
    fc1b16[j] = tobf(fc1w[j]);
  }
}

// ---------------- 2. fused mid: topk(1 blk) | LOI GEMM (256 blks) | w1/w2 cast ----
__global__ __launch_bounds__(1024) void k_mid(
    const unsigned long long* __restrict__ cand, const int* __restrict__ cand_count,
    const float* __restrict__ hm, float* __restrict__ junc,
    const short* __restrict__ featT, const short* __restrict__ fc1b16,
    const float* __restrict__ fc1b, short* __restrict__ loi,
    const float* __restrict__ w1, const float* __restrict__ w2,
    short* __restrict__ w1b, short* __restrict__ w2b){
  __shared__ __align__(16) char smem[CAND_CAP*8];   // 32 KB union
  int b = blockIdx.x, t = threadIdx.x;
  if (b == 0){
    // ---- bitonic top-K ----
    unsigned long long* s = (unsigned long long*)smem;
    int count = *cand_count; if (count > CAND_CAP) count = CAND_CAP;
    int n2 = 512;
    while (n2 < count) n2 <<= 1;
    for (int i=t; i<n2; i+=1024) s[i] = (i < count) ? cand[i] : 0ull;
    __syncthreads();
    for (int k=2; k<=n2; k<<=1){
      for (int j=k>>1; j>0; j>>=1){
        for (int i=t; i<n2; i+=1024){
          int ixj = i ^ j;
          if (ixj > i){
            unsigned long long a = s[i], bb = s[ixj];
            bool desc = ((i & k) == 0);
            if (desc ? (a < bb) : (a > bb)){ s[i] = bb; s[ixj] = a; }
          }
        }
        __syncthreads();
      }
    }
    if (t < KJ){
      float jx = 1e6f, jy = 1e6f;
      if (t < count){
        unsigned idx = 0xFFFFFFFFu - (unsigned)(s[t] & 0xFFFFFFFFull);
        int yy = (int)(idx >> 7), xx = (int)(idx & 127u);
        jx = (float)xx + sigm(hm[7*HW + idx]);
        jy = (float)yy + sigm(hm[8*HW + idx]);
      }
      junc[2*t] = jx; junc[2*t+1] = jy;
    }
  } else if (b <= 256){
    // ---- LOI GEMM: featT[HW,256] @ fc1w[128,256]^T -> loi[HW,128] bf16 ----
    if (t >= 256) return;
    short* As = (short*)smem;            // 8 KB: 64 rows x 64
    short* Bs = (short*)(smem + 8192);   // 16 KB: 128 rows x 64
    int rb = (b - 1) * 64;
    int lane = t & 63, wave = t >> 6;
    int l16 = lane & 15, quad = lane >> 4;
    int srow = lane >> 3, schunk = (lane & 7) ^ srow;
    f32x4 acc[8];
    #pragma unroll
    for (int g=0; g<8; g++) acc[g] = (f32x4){0,0,0,0};
    for (int k0=0; k0<256; k0+=64){
      #pragma unroll
      for (int i=0; i<2; i++){
        int r0 = wave*16 + i*8;
        GLOAD_LDS16(featT + (size_t)(rb + r0 + srow)*256 + k0 + schunk*8, &As[r0*64]);
      }
      #pragma unroll
      for (int i=0; i<4; i++){
        int r0 = wave*32 + i*8;
        GLOAD_LDS16(fc1b16 + (size_t)(r0 + srow)*256 + k0 + schunk*8, &Bs[r0*64]);
      }
      __syncthreads();
      #pragma unroll
      for (int s2=0; s2<2; s2++){
        int slot = (s2*4 + quad) ^ (l16 & 7);
        bf16x8 a = *(const bf16x8*)&As[(wave*16 + l16)*64 + slot*8];
        #pragma unroll
        for (int g=0; g<8; g++){
          bf16x8 bv = *(const bf16x8*)&Bs[(g*16 + l16)*64 + slot*8];
          acc[g] = __builtin_amdgcn_mfma_f32_16x16x32_bf16(a, bv, acc[g], 0, 0, 0);
        }
      }
      __syncthreads();
    }
    int rowbase = rb + wave*16 + quad*4;
    #pragma unroll
    for (int g=0; g<8; g++){
      int col = g*16 + l16;
      float bs = fc1b[col];
      #pragma unroll
      for (int r=0; r<4; r++)
        loi[(size_t)(rowbase + r)*128 + col] = tobf(acc[g][r] + bs);
    }
  } else {
    int j = (b - 257)*1024 + t;   // < 1M
    w1b[j] = tobf(w1[j]);
    w2b[j] = tobf(w2[j]);
  }
}

// ---------------- 3. junction-endpoint argmin matching ----------------
__global__ void k_match(const float* __restrict__ lines, const float* __restrict__ junc,
                        int* __restrict__ ids){
  __shared__ float jx[KJ], jy[KJ];
  int t = threadIdx.x;
  for (int k=t; k<KJ; k+=blockDim.x){ jx[k] = junc[2*k]; jy[k] = junc[2*k+1]; }
  __syncthreads();
  int n = blockIdx.x*blockDim.x + t;
  if (n >= NLINES) return;
  float4 L = ((const float4*)lines)[n];
  float b1 = 1e30f, b2 = 1e30f; int j1 = 0, j2 = 0;
  #pragma unroll 4
  for (int k=0; k<KJ; k++){
    float dx1 = jx[k]-L.x, dy1 = jy[k]-L.y;
    float d1 = dx1*dx1 + dy1*dy1;
    float dx2 = jx[k]-L.z, dy2 = jy[k]-L.w;
    float d2 = dx2*dx2 + dy2*dy2;
    if (d1 < b1){ b1 = d1; j1 = k; }
    if (d2 < b2){ b2 = d2; j2 = k; }
  }
  int lo = min(j1,j2), hi = max(j1,j2);
  ids[n] = (lo < hi) ? (lo*KJ + hi) : SENT;
}

// ---------------- 4. sorted unique via bitmap + shuffle scan ----------------
__global__ __launch_bounds__(1024) void k_unique(const int* __restrict__ ids,
    int* __restrict__ uid_list, int* __restrict__ mcount){
  __shared__ unsigned bm[BITWORDS];
  __shared__ int wsum[16];
  int t = threadIdx.x;
  for (int i=t; i<BITWORDS; i+=1024) bm[i] = 0u;
  __syncthreads();
  for (int n=t; n<NLINES; n+=1024){
    int id = ids[n];
    if (id < SENT) atomicOr(&bm[id>>5], 1u << (id & 31));
  }
  __syncthreads();
  int w0 = t*3;
  int local = 0;
  for (int w=w0; w<w0+3; w++) if (w < BITWORDS) local += __popc(bm[w]);
  int v = local;
  #pragma unroll
  for (int d=1; d<64; d<<=1){
    int nv = __shfl_up(v, d, 64);
    if ((t & 63) >= d) v += nv;
  }
  if ((t & 63) == 63) wsum[t >> 6] = v;
  __syncthreads();
  if (t < 16){
    int x = wsum[t];
    #pragma unroll
    for (int d=1; d<16; d<<=1){
      int nv = __shfl_up(x, d, 16);
      if (t >= d) x += nv;
    }
    wsum[t] = x;
  }
  __syncthreads();
  int base = v - local + ((t >> 6) ? wsum[(t >> 6) - 1] : 0);
  for (int w=w0; w<w0+3; w++){
    if (w >= BITWORDS) break;
    unsigned bits = bm[w];
    while (bits){
      int bb = __ffs(bits) - 1;
      uid_list[base++] = w*32 + bb;
      bits &= bits - 1;
    }
  }
  if (t == 1023) *mcount = base;
}

// ---------------- 5. line_coords output (+ zero scores past M) ----------------
__global__ void k_coords(const int* __restrict__ uid_list, const int* __restrict__ mcount,
                         const float* __restrict__ junc, float* __restrict__ out){
  int r = blockIdx.x*blockDim.x + threadIdx.x;
  if (r >= NLINES) return;
  int M = *mcount;
  float4 v = make_float4(0.f,0.f,0.f,0.f);
  if (r < M){
    int id = uid_list[r];
    int lo = id / KJ, hi = id % KJ;
    v = make_float4(junc[2*lo], junc[2*lo+1], junc[2*hi], junc[2*hi+1]);
  } else {
    out[4*NLINES + r] = 0.0f;
  }
  ((float4*)out)[r] = v;
}

// ---------------- 6. sampling + cnt/logit init ----------------
__global__ __launch_bounds__(256) void k_sample(const float* __restrict__ out,
    const short* __restrict__ loi, const int* __restrict__ mcount,
    short* __restrict__ fbuf, float* __restrict__ logit, int* __restrict__ cnt,
    int ncnt, int chunk0, int chunk){
  __shared__ int4   sOffs[32];
  __shared__ float4 sWts[32];
  int M = *mcount;
  int t = threadIdx.x;
  if (t == 0 && blockIdx.x < ncnt) cnt[blockIdx.x] = 0;
  int q  = t >> 6;
  int c2 = (t & 63) << 1;
  for (int l = blockIdx.x; l < chunk && chunk0 + l < M; l += gridDim.x){
    int r = chunk0 + l;
    if (t == 0) logit[l] = 0.0f;
    __syncthreads();
    if (t < 32){
      float4 C = ((const float4*)out)[r];
      float tt = (float)t * (1.0f/31.0f);
      float px = C.x*tt + C.z*(1.0f-tt);
      float py = C.y*tt + C.w*(1.0f-tt);
      px = fminf(fmaxf(px, 0.0f), 127.0f);
      py = fminf(fmaxf(py, 0.0f), 127.0f);
      float x0 = floorf(px), y0 = floorf(py);
      int x0i = (int)x0, y0i = (int)y0;
      int x1i = min(x0i+1, 127), y1i = min(y0i+1, 127);
      float wx = px - x0, wy = py - y0;
      sOffs[t] = make_int4((y0i*WW + x0i)*128, (y0i*WW + x1i)*128,
                           (y1i*WW + x0i)*128, (y1i*WW + x1i)*128);
      sWts[t]  = make_float4((1.0f-wx)*(1.0f-wy), wx*(1.0f-wy),
                             (1.0f-wx)*wy,        wx*wy);
    }
    __syncthreads();
    float gl0=-1e30f, gl1=-1e30f, gh0=-1e30f, gh1=-1e30f;
    #pragma unroll
    for (int j=0; j<8; j++){
      int s = q*8 + j;
      int4 o   = sOffs[s];
      float4 w = sWts[s];
      unsigned u00 = *(const unsigned*)&loi[o.x + c2];
      unsigned u01 = *(const unsigned*)&loi[o.y + c2];
      unsigned u10 = *(const unsigned*)&loi[o.z + c2];
      unsigned u11 = *(const unsigned*)&loi[o.w + c2];
      float vlo = w.x*bflo(u00) + w.y*bflo(u01) + w.z*bflo(u10) + w.w*bflo(u11);
      float vhi = w.x*bfhi(u00) + w.y*bfhi(u01) + w.z*bfhi(u10) + w.w*bfhi(u11);
      if (j < 4){ gl0 = fmaxf(gl0, vlo); gh0 = fmaxf(gh0, vhi); }
      else      { gl1 = fmaxf(gl1, vlo); gh1 = fmaxf(gh1, vhi); }
    }
    unsigned plo = ((unsigned)(unsigned short)tobf(gl0)) | (((unsigned)(unsigned short)tobf(gl1)) << 16);
    unsigned phi = ((unsigned)(unsigned short)tobf(gh0)) | (((unsigned)(unsigned short)tobf(gh1)) << 16);
    *(unsigned*)&fbuf[(size_t)l*1024 + c2*8 + q*2]     = plo;
    *(unsigned*)&fbuf[(size_t)l*1024 + (c2+1)*8 + q*2] = phi;
  }
}

// ---------------- 7. 128x128-tile MFMA MLP GEMM ----------------
// MODE 0: Hout bf16 = relu(C + bias)
// MODE 2: logit += relu(C + bias).w3 ; last col-block applies sigmoid -> out
template<int MODE>
__global__ __launch_bounds__(256) void k_mlp(const short* __restrict__ A,
    const short* __restrict__ B, const float* __restrict__ bias,
    short* __restrict__ Hout, const float* __restrict__ w3,
    const float* __restrict__ b3, float* __restrict__ logit,
    int* __restrict__ cnt, const int* __restrict__ mcount,
    int chunk0, float* __restrict__ outScore){
  int M = *mcount;
  int rb = blockIdx.x * 128;
  if (chunk0 + rb >= M) return;
  int cb = blockIdx.y * 128;
  __shared__ short As[128*64];   // 16 KB
  __shared__ short Bs[128*64];   // 16 KB
  __shared__ int sflag;
  int lane = threadIdx.x & 63, wave = threadIdx.x >> 6;
  int l16 = lane & 15, quad = lane >> 4;
  int srow = lane >> 3, schunk = (lane & 7) ^ srow;
  f32x4 acc0[8], acc1[8];
  #pragma unroll
  for (int g=0; g<8; g++){ acc0[g] = (f32x4){0,0,0,0}; acc1[g] = (f32x4){0,0,0,0}; }
  for (int k0=0; k0<1024; k0+=64){
    #pragma unroll
    for (int i=0; i<4; i++){
      int r0 = wave*32 + i*8;
      GLOAD_LDS16(A + (size_t)(rb + r0 + srow)*1024 + k0 + schunk*8, &As[r0*64]);
      GLOAD_LDS16(B + (size_t)(cb + r0 + srow)*1024 + k0 + schunk*8, &Bs[r0*64]);
    }
    __syncthreads();
    #pragma unroll
    for (int s=0; s<2; s++){
      int slot = (s*4 + quad) ^ (l16 & 7);
      bf16x8 a0 = *(const bf16x8*)&As[(wave*32 + l16)*64 + slot*8];
      bf16x8 a1 = *(const bf16x8*)&As[(wave*32 + 16 + l16)*64 + slot*8];
      #pragma unroll
      for (int g=0; g<8; g++){
        bf16x8 bv = *(const bf16x8*)&Bs[(g*16 + l16)*64 + slot*8];
        acc0[g] = __builtin_amdgcn_mfma_f32_16x16x32_bf16(a0, bv, acc0[g], 0, 0, 0);
        acc1[g] = __builtin_amdgcn_mfma_f32_16x16x32_bf16(a1, bv, acc1[g], 0, 0, 0);
      }
    }
    __syncthreads();
  }
  int r0b = rb + wave*32 + quad*4;
  int r1b = r0b + 16;
  if (MODE == 0){
    #pragma unroll
    for (int g=0; g<8; g++){
      int col = cb + g*16 + l16;
      float bs = bias[col];
      #pragma unroll
      for (int r=0; r<4; r++){
        Hout[(size_t)(r0b + r)*1024 + col] = tobf(fmaxf(acc0[g][r] + bs, 0.0f));
        Hout[(size_t)(r1b + r)*1024 + col] = tobf(fmaxf(acc1[g][r] + bs, 0.0f));
      }
    }
  } else {
    float p0[4] = {0,0,0,0}, p1[4] = {0,0,0,0};
    #pragma unroll
    for (int g=0; g<8; g++){
      int col = cb + g*16 + l16;
      float bs = bias[col], wv = w3[col];
      #pragma unroll
      for (int r=0; r<4; r++){
        p0[r] += fmaxf(acc0[g][r] + bs, 0.0f) * wv;
        p1[r] += fmaxf(acc1[g][r] + bs, 0.0f) * wv;
      }
    }
    #pragma unroll
    for (int r=0; r<4; r++){
      #pragma unroll
      for (int m=1; m<16; m<<=1){
        p0[r] += __shfl_xor(p0[r], m, 16);
        p1[r] += __shfl_xor(p1[r], m, 16);
      }
    }
    if (l16 == 0){
      #pragma unroll
      for (int r=0; r<4; r++){
        atomicAdd(&logit[r0b + r], p0[r]);
        atomicAdd(&logit[r1b + r], p1[r]);
      }
    }
    __syncthreads();
    if (threadIdx.x == 0){
      __threadfence();
      int old = atomicAdd(&cnt[blockIdx.x], 1);
      sflag = (old == 7) ? 1 : 0;
    }
    __syncthreads();
    if (sflag){
      __threadfence();
      if (threadIdx.x < 128){
        int row = rb + threadIdx.x;
        int rg = chunk0 + row;
        if (rg < M){
          float lg = atomicAdd(&logit[row], 0.0f) + b3[0];  // coherent read
          outScore[4*NLINES + rg] = 1.0f/(1.0f + expf(-lg));
        }
      }
    }
  }
}

extern "C" void kernel_launch(void* const* d_in, const int* in_sizes, int n_in,
                              void* d_out, int out_size, void* d_ws, size_t ws_size,
                              hipStream_t stream){
  const float* features = (const float*)d_in[0];
  const float* heatmaps = (const float*)d_in[1];
  const float* fc1_w    = (const float*)d_in[2];
  const float* fc1_b    = (const float*)d_in[3];
  const float* w1       = (const float*)d_in[4];
  const float* b1       = (const float*)d_in[5];
  const float* w2       = (const float*)d_in[6];
  const float* b2       = (const float*)d_in[7];
  const float* w3       = (const float*)d_in[8];
  const float* b3       = (const float*)d_in[9];
  float* out = (float*)d_out;

  char* ws = (char*)d_ws;
  size_t off = 0;
  auto alloc = [&](size_t bytes) -> void* {
    void* p = ws + off;
    off = (off + bytes + 255) & ~(size_t)255;
    return p;
  };
  float* lines     = (float*)alloc((size_t)NLINES*16);
  unsigned long long* cand = (unsigned long long*)alloc(CAND_CAP*8);
  int*   cand_count= (int*)alloc(4);
  float* junc      = (float*)alloc(KJ*2*4);
  int*   ids       = (int*)alloc((size_t)NLINES*4);
  int*   uid_list  = (int*)alloc((size_t)NLINES*4);
  int*   mcount    = (int*)alloc(4);
  int*   cnt       = (int*)alloc((NLINES/128)*4);
  short* loi       = (short*)alloc((size_t)HW*128*2);
  short* featT     = (short*)alloc((size_t)HW*256*2);
  short* fc1b16    = (short*)alloc((size_t)128*256*2);
  short* w1b       = (short*)alloc((size_t)1024*1024*2);
  short* w2b       = (short*)alloc((size_t)1024*1024*2);
  size_t fixed = off;

  const int chunk_opts[7] = {49152, 24576, 12288, 8192, 4096, 2048, 1024};
  int CHUNK = 1024;
  for (int ci=0; ci<7; ci++){
    size_t need = fixed + (size_t)chunk_opts[ci]*1024*2*2 + (size_t)chunk_opts[ci]*4 + 1024;
    if (need <= ws_size){ CHUNK = chunk_opts[ci]; break; }
  }
  short* fbuf  = (short*)alloc((size_t)CHUNK*1024*2);
  short* h1buf = (short*)alloc((size_t)CHUNK*1024*2);
  float* logit = (float*)alloc((size_t)CHUNK*4);

  hipMemsetAsync(cand_count, 0, 4, stream);
  k_front<<<4288, 256, 0, stream>>>(heatmaps, features, fc1_w, lines, cand,
                                    cand_count, featT, fc1b16);
  k_mid  <<<1281, 1024, 0, stream>>>(cand, cand_count, heatmaps, junc, featT,
                                     fc1b16, fc1_b, loi, w1, w2, w1b, w2b);
  k_match<<<NLINES/256, 256, 0, stream>>>(lines, junc, ids);
  k_unique<<<1, 1024, 0, stream>>>(ids, uid_list, mcount);
  k_coords<<<NLINES/256, 256, 0, stream>>>(uid_list, mcount, junc, out);

  int nchunk = NLINES / CHUNK;
  for (int ci=0; ci<nchunk; ci++){
    int chunk0 = ci * CHUNK;
    k_sample<<<2048, 256, 0, stream>>>(out, loi, mcount, fbuf, logit, cnt,
                                       CHUNK/128, chunk0, CHUNK);
    dim3 g1(CHUNK/128, 8);
    k_mlp<0><<<g1, 256, 0, stream>>>(fbuf, w1b, b1, h1buf, nullptr, nullptr,
                                     nullptr, nullptr, mcount, chunk0, nullptr);
    k_mlp<2><<<g1, 256, 0, stream>>>(h1buf, w2b, b2, nullptr, w3, b3,
                                     logit, cnt, mcount, chunk0, out);
  }
}